// Round 3
// baseline (11455.874 us; speedup 1.0000x reference)
//
#include <hip/hip_runtime.h>
#include <math.h>

#define S_LEN 215
#define NB    512
#define DI    36
#define DMODEL 144
#define DT    160
#define NH    4
#define DH    40
#define NHID  128
#define FIN   860
#define DFIN  196
#define CDIV(a,b) (((a)+(b)-1)/(b))

// ---------------- build x chunk: Xc[bl,i,s*4+o] = relu(src[s,b0+bl,i] * R_u[i*4+o]) ----------------
__global__ __launch_bounds__(256) void zz_build_x(const float* __restrict__ src,
    const float* __restrict__ R_u, float* __restrict__ X, int b0, int CB)
{
  int idx = blockIdx.x*256 + threadIdx.x;           // (bl,i,s)
  if (idx >= CB*DI*S_LEN) return;
  int s = idx % S_LEN; int t = idx / S_LEN; int i = t % DI; int bl = t / DI;
  float v = src[((size_t)s*NB + b0 + bl)*(2*DI) + i];
  float4 r = *(const float4*)(R_u + i*4);
  float4 o;
  o.x = fmaxf(v*r.x, 0.f); o.y = fmaxf(v*r.y, 0.f);
  o.z = fmaxf(v*r.z, 0.f); o.w = fmaxf(v*r.w, 0.f);
  *(float4*)(X + (size_t)(bl*DI + i)*FIN + s*4) = o;
}

// ---------------- positional encoding into XCH cols 144..159 (chunk tokens tl = s*CB+bl) ----------------
__global__ __launch_bounds__(256) void zz_pe(const float* __restrict__ times,
    float* __restrict__ XCH, int b0, int CB)
{
  int idx = blockIdx.x*256 + threadIdx.x;           // (tl, k)
  if (idx >= CB*S_LEN*16) return;
  int k = idx & 15; int tl = idx >> 4;
  int bl = tl % CB; int s = tl / CB;
  int j = k & 7;
  float ts = powf(215.f, (float)j * (1.f/7.f)) * 100.f;
  float sc = times[(size_t)s*NB + b0 + bl] / ts;
  XCH[(size_t)tl*DT + DMODEL + k] = (k < 8) ? sinf(sc) : cosf(sc);
}

// ---------------- emb = static @ emb_w + emb_b (full batch) ----------------
__global__ __launch_bounds__(256) void zz_emb(const float* __restrict__ st,
    const float* __restrict__ w, const float* __restrict__ bias, float* __restrict__ emb)
{
  int idx = blockIdx.x*256 + threadIdx.x;
  if (idx >= NB*DI) return;
  int b = idx / DI, k = idx % DI;
  float acc = bias[k];
  #pragma unroll
  for (int j = 0; j < 9; ++j) acc = fmaf(st[b*9 + j], w[j*DI + k], acc);
  emb[idx] = acc;
}

// ---------------- per-sample GEMM: XP[bl] = Xin[bl](36x860) @ W(860x860) ----------------
__global__ __launch_bounds__(256) void zz_gat_gemm(const float* __restrict__ Xin,
    const float* __restrict__ W, float* __restrict__ XP)
{
  __shared__ float As[DI][33];    // [m][kk]
  __shared__ float Ws[32][129];   // [kk][n]
  int bl = blockIdx.y, n0 = blockIdx.x * 128;
  int tid = threadIdx.x;
  int n = tid & 127, mg = tid >> 7;    // mg in {0,1}: rows mg*18..mg*18+17
  const float* Xb = Xin + (size_t)bl*DI*FIN;
  float acc[18] = {};
  for (int k0 = 0; k0 < FIN; k0 += 32) {
    for (int i = tid; i < DI*32; i += 256) {
      int m = i >> 5, kk = i & 31, gk = k0 + kk;
      As[m][kk] = (gk < FIN) ? Xb[m*FIN + gk] : 0.f;
    }
    for (int i = tid; i < 32*128; i += 256) {
      int kk = i >> 7, nn = i & 127;
      int gk = k0 + kk, gn = n0 + nn;
      Ws[kk][nn] = (gk < FIN && gn < FIN) ? W[(size_t)gk*FIN + gn] : 0.f;
    }
    __syncthreads();
    #pragma unroll 8
    for (int kk = 0; kk < 32; ++kk) {
      float wv = Ws[kk][n];
      #pragma unroll
      for (int m = 0; m < 18; ++m)
        acc[m] = fmaf(As[mg*18 + m][kk], wv, acc[m]);
    }
    __syncthreads();
  }
  int gn = n0 + n;
  if (gn < FIN) {
    float* XPb = XP + (size_t)bl*DI*FIN;
    #pragma unroll
    for (int m = 0; m < 18; ++m) XPb[(mg*18 + m)*FIN + gn] = acc[m];
  }
}

// ---------------- per-row dots: ss[b,i]=xp[bl,i,:]·a_s, sd=·a_d (global SS/SD) ----------------
__global__ __launch_bounds__(64) void zz_gat_attvec(const float* __restrict__ XP,
    const float* __restrict__ a_s, const float* __restrict__ a_d,
    float* __restrict__ ss, float* __restrict__ sd, int b0)
{
  int i = blockIdx.x, bl = blockIdx.y, lane = threadIdx.x;
  const float* row = XP + ((size_t)bl*DI + i)*FIN;
  float ps = 0.f, pd = 0.f;
  for (int k = lane; k < FIN; k += 64) {
    float v = row[k];
    ps = fmaf(v, a_s[k], ps);
    pd = fmaf(v, a_d[k], pd);
  }
  for (int off = 32; off; off >>= 1) { ps += __shfl_xor(ps, off); pd += __shfl_xor(pd, off); }
  if (!lane) { ss[(b0 + bl)*DI + i] = ps; sd[(b0 + bl)*DI + i] = pd; }
}

// ---------------- alpha[b,i,j] = softmax_j(lrelu(sd_i + ss_j)) * edge (global alpha) ----------------
__global__ __launch_bounds__(256) void zz_gat_alpha(const float* __restrict__ ss,
    const float* __restrict__ sd, const float* __restrict__ edge, float* __restrict__ alpha, int b0)
{
  int b = b0 + blockIdx.x;
  int wv = threadIdx.x >> 6, lane = threadIdx.x & 63;
  for (int i = wv; i < DI; i += 4) {
    float di = sd[b*DI + i];
    float e = -3e38f, x = 0.f;
    if (lane < DI) {
      x = di + ss[b*DI + lane];
      x = (x >= 0.f) ? x : 0.2f*x;
      e = x;
    }
    float m = e;
    for (int off = 32; off; off >>= 1) m = fmaxf(m, __shfl_xor(m, off));
    float p = (lane < DI) ? expf(e - m) : 0.f;
    float s = p;
    for (int off = 32; off; off >>= 1) s += __shfl_xor(s, off);
    if (lane < DI) {
      float a = p / s;
      size_t o = ((size_t)b*DI + i)*DI + lane;
      if (edge) a *= edge[o];
      alpha[o] = a;
    }
  }
}

// ---------------- h[bl] = alpha[b](36x36) @ XP[bl](36x860); mode1 scatters to XCH(tl,160) ----------------
__global__ __launch_bounds__(256) void zz_gat_apply(const float* __restrict__ alpha,
    const float* __restrict__ XP, float* __restrict__ out, int mode, int b0, int CB)
{
  __shared__ float Al[DI][37];
  __shared__ float Xs[DI][129];
  int bl = blockIdx.y, n0 = blockIdx.x * 128;
  int tid = threadIdx.x;
  int n = tid & 127, mg = tid >> 7;
  const float* ab = alpha + ((size_t)(b0 + bl))*DI*DI;
  for (int i = tid; i < DI*DI; i += 256) Al[i/DI][i%DI] = ab[i];
  const float* XPb = XP + (size_t)bl*DI*FIN;
  for (int i = tid; i < DI*128; i += 256) {
    int k = i >> 7, nn = i & 127, gn = n0 + nn;
    Xs[k][nn] = (gn < FIN) ? XPb[k*FIN + gn] : 0.f;
  }
  __syncthreads();
  float acc[18] = {};
  #pragma unroll 4
  for (int k = 0; k < DI; ++k) {
    float xv = Xs[k][n];
    #pragma unroll
    for (int m = 0; m < 18; ++m)
      acc[m] = fmaf(Al[mg*18 + m][k], xv, acc[m]);
  }
  int gn = n0 + n;
  if (gn < FIN) {
    if (mode == 0) {
      float* ob = out + (size_t)bl*DI*FIN;
      #pragma unroll
      for (int m = 0; m < 18; ++m) ob[(mg*18 + m)*FIN + gn] = acc[m];
    } else {
      int s = gn >> 2, o = gn & 3;   // channel = i*4+o
      float* op = out + ((size_t)s*CB + bl)*DT + o;
      #pragma unroll
      for (int m = 0; m < 18; ++m) op[(mg*18 + m)*4] = acc[m];
    }
  }
}

// ---------------- distance helpers (full batch, on global A2) ----------------
__global__ __launch_bounds__(64) void zz_sq(const float* __restrict__ A, float* __restrict__ sq)
{
  int i = blockIdx.x, lane = threadIdx.x;
  const float* row = A + (size_t)i*(DI*DI);
  float s = 0.f;
  for (int k = lane; k < DI*DI; k += 64) { float v = row[k]; s = fmaf(v, v, s); }
  for (int off = 32; off; off >>= 1) s += __shfl_xor(s, off);
  if (!lane) sq[i] = s;
}

__global__ __launch_bounds__(256) void zz_dist(const float* __restrict__ A,
    const float* __restrict__ sq, float* __restrict__ dsum)
{
  __shared__ float Ai[64][65], Aj[64][65];
  __shared__ float red[256];
  int i0 = blockIdx.y*64, j0 = blockIdx.x*64;
  int tid = threadIdx.x, tx = tid % 16, ty = tid / 16;
  float acc[4][4] = {};
  for (int k0 = 0; k0 < DI*DI; k0 += 64) {
    for (int t = tid; t < 64*64; t += 256) {
      int r = t >> 6, kk = t & 63, gk = k0 + kk;
      float vi = 0.f, vj = 0.f;
      if (gk < DI*DI) {
        vi = A[(size_t)(i0 + r)*(DI*DI) + gk];
        vj = A[(size_t)(j0 + r)*(DI*DI) + gk];
      }
      Ai[r][kk] = vi; Aj[r][kk] = vj;
    }
    __syncthreads();
    #pragma unroll 8
    for (int kk = 0; kk < 64; ++kk) {
      float a[4], bb[4];
      #pragma unroll
      for (int u = 0; u < 4; ++u) a[u]  = Ai[ty*4 + u][kk];
      #pragma unroll
      for (int u = 0; u < 4; ++u) bb[u] = Aj[tx*4 + u][kk];
      #pragma unroll
      for (int u = 0; u < 4; ++u)
        #pragma unroll
        for (int v = 0; v < 4; ++v) acc[u][v] = fmaf(a[u], bb[v], acc[u][v]);
    }
    __syncthreads();
  }
  float s = 0.f;
  #pragma unroll
  for (int u = 0; u < 4; ++u)
    #pragma unroll
    for (int v = 0; v < 4; ++v) {
      float d2 = sq[i0 + ty*4 + u] + sq[j0 + tx*4 + v] - 2.f*acc[u][v];
      d2 = fmaxf(d2, 0.f);
      s += sqrtf(d2 + 1e-12f);
    }
  red[tid] = s; __syncthreads();
  for (int st = 128; st; st >>= 1) { if (tid < st) red[tid] += red[tid + st]; __syncthreads(); }
  if (!tid) atomicAdd(dsum, red[0]);
}

__global__ void zz_dist_fin(const float* dsum, float* out)
{
  out[0] = dsum[0] * (1.f/((float)NB*(float)NB));
}

// ---------------- generic tiled f32 GEMM: C = [relu]( A(MxK)@B(KxN) + bias [+ res] ) ----------------
template<int RELU, int RES>
__global__ __launch_bounds__(256) void zz_gemm(const float* __restrict__ A,
    const float* __restrict__ Bw, const float* __restrict__ bias,
    const float* __restrict__ res, float* __restrict__ C, int M, int N, int K)
{
  __shared__ float As[32][65];  // [kk][m]
  __shared__ float Bs[32][65];  // [kk][n]
  int m0 = blockIdx.y*64, n0 = blockIdx.x*64;
  int tid = threadIdx.x, tx = tid % 16, ty = tid / 16;
  float acc[4][4] = {};
  for (int k0 = 0; k0 < K; k0 += 32) {
    for (int i = tid; i < 64*32; i += 256) {
      int r = i >> 5, kk = i & 31;
      int gm = m0 + r, gk = k0 + kk;
      As[kk][r] = (gm < M && gk < K) ? A[(size_t)gm*K + gk] : 0.f;
    }
    for (int i = tid; i < 32*64; i += 256) {
      int kk = i >> 6, n = i & 63;
      int gk = k0 + kk, gn = n0 + n;
      Bs[kk][n] = (gk < K && gn < N) ? Bw[(size_t)gk*N + gn] : 0.f;
    }
    __syncthreads();
    #pragma unroll 8
    for (int kk = 0; kk < 32; ++kk) {
      float a[4], b[4];
      #pragma unroll
      for (int u = 0; u < 4; ++u) a[u] = As[kk][ty*4 + u];
      #pragma unroll
      for (int v = 0; v < 4; ++v) b[v] = Bs[kk][tx*4 + v];
      #pragma unroll
      for (int u = 0; u < 4; ++u)
        #pragma unroll
        for (int v = 0; v < 4; ++v) acc[u][v] = fmaf(a[u], b[v], acc[u][v]);
    }
    __syncthreads();
  }
  #pragma unroll
  for (int u = 0; u < 4; ++u) {
    int gm = m0 + ty*4 + u;
    if (gm >= M) continue;
    #pragma unroll
    for (int v = 0; v < 4; ++v) {
      int gn = n0 + tx*4 + v;
      if (gn >= N) continue;
      float val = acc[u][v] + bias[gn];
      if (RES) val += res[(size_t)gm*N + gn];
      if (RELU) val = fmaxf(val, 0.f);
      C[(size_t)gm*N + gn] = val;
    }
  }
}

// ---------------- attention: one block per (bl,h), chunk-local QKV/O ----------------
__global__ __launch_bounds__(256) void zz_attn(const float* __restrict__ QKV,
    const int* __restrict__ lengths, float* __restrict__ O, int b0, int CB)
{
  __shared__ float Kl[S_LEN][DH+1];
  __shared__ float Vl[S_LEN][DH+1];
  __shared__ float qs[DH];
  __shared__ float pbuf[S_LEN];
  __shared__ float wred[8];
  __shared__ float pacc[256];
  int bh = blockIdx.x, bl = bh >> 2, h = bh & 3;
  int tid = threadIdx.x, wv = tid >> 6, lane = tid & 63;
  int len = lengths[b0 + bl];
  for (int i = tid; i < S_LEN*DH; i += 256) {
    int s = i / DH, d = i - s*DH;
    const float* base = QKV + ((size_t)s*CB + bl)*(3*DT) + h*DH + d;
    Kl[s][d] = base[DT];
    Vl[s][d] = base[2*DT];
  }
  __syncthreads();
  for (int sq = 0; sq < S_LEN; ++sq) {
    if (tid < DH) qs[tid] = QKV[((size_t)sq*CB + bl)*(3*DT) + h*DH + tid];
    __syncthreads();
    float sc = 0.f;
    if (tid < S_LEN) {
      #pragma unroll
      for (int d = 0; d < DH; ++d) sc = fmaf(qs[d], Kl[tid][d], sc);
      sc *= 0.15811388300841897f;     // 1/sqrt(40)
      if (tid >= len) sc = -1e9f;
    }
    float e = (tid < S_LEN) ? sc : -3e38f;
    float m = e;
    for (int off = 32; off; off >>= 1) m = fmaxf(m, __shfl_xor(m, off));
    if (!lane) wred[wv] = m;
    __syncthreads();
    float mx = fmaxf(fmaxf(wred[0], wred[1]), fmaxf(wred[2], wred[3]));
    float p = (tid < S_LEN) ? expf(sc - mx) : 0.f;
    if (tid < S_LEN) pbuf[tid] = p;
    float s2 = p;
    for (int off = 32; off; off >>= 1) s2 += __shfl_xor(s2, off);
    if (!lane) wred[4 + wv] = s2;
    __syncthreads();
    float inv = 1.f / (wred[4] + wred[5] + wred[6] + wred[7]);
    float acc = 0.f;
    int d = tid >> 2, qq = tid & 3;
    if (d < DH) {
      for (int t = qq; t < S_LEN; t += 4) acc = fmaf(pbuf[t], Vl[t][d], acc);
    }
    pacc[tid] = acc;
    __syncthreads();
    if (tid < DH) {
      float o = (pacc[tid*4] + pacc[tid*4+1] + pacc[tid*4+2] + pacc[tid*4+3]) * inv;
      O[((size_t)sq*CB + bl)*DT + h*DH + tid] = o;
    }
    __syncthreads();
  }
}

// ---------------- layernorm over 160, one wave per token ----------------
__global__ __launch_bounds__(256) void zz_ln(const float* __restrict__ X,
    const float* __restrict__ g, const float* __restrict__ bt, float* __restrict__ Y, int ntok)
{
  int tok = blockIdx.x*4 + (threadIdx.x >> 6);
  if (tok >= ntok) return;
  int lane = threadIdx.x & 63;
  const float* x = X + (size_t)tok*DT;
  float v0 = x[lane], v1 = x[lane + 64];
  float v2 = (lane < 32) ? x[lane + 128] : 0.f;
  float s = v0 + v1 + v2;
  for (int off = 32; off; off >>= 1) s += __shfl_xor(s, off);
  float mean = s * (1.f/160.f);
  float d0 = v0 - mean, d1 = v1 - mean, d2 = (lane < 32) ? (v2 - mean) : 0.f;
  float q = d0*d0 + d1*d1 + d2*d2;
  for (int off = 32; off; off >>= 1) q += __shfl_xor(q, off);
  float inv = 1.f / sqrtf(q * (1.f/160.f) + 1e-5f);
  float* y = Y + (size_t)tok*DT;
  y[lane]      = d0*inv*g[lane]      + bt[lane];
  y[lane + 64] = d1*inv*g[lane + 64] + bt[lane + 64];
  if (lane < 32) y[lane + 128] = d2*inv*g[lane + 128] + bt[lane + 128];
}

// ---------------- masked mean + feat concat (per chunk) ----------------
__global__ __launch_bounds__(256) void zz_agg(const float* __restrict__ XCH,
    const int* __restrict__ lengths, const float* __restrict__ emb, float* __restrict__ feat,
    int b0, int CB)
{
  int bl = blockIdx.x, tid = threadIdx.x;
  int b = b0 + bl;
  int len = lengths[b];
  if (tid < DT) {
    float acc = 0.f;
    for (int s = 0; s < len; ++s) acc += XCH[((size_t)s*CB + bl)*DT + tid];
    feat[(size_t)b*DFIN + tid] = acc / (float)(len + 1);
  } else if (tid < DFIN) {
    feat[(size_t)b*DFIN + tid] = emb[b*DI + (tid - DT)];
  }
}

// ======================================================================
extern "C" void kernel_launch(void* const* d_in, const int* in_sizes, int n_in,
                              void* d_out, int out_size, void* d_ws, size_t ws_size,
                              hipStream_t stream)
{
  (void)in_sizes; (void)n_in; (void)out_size;
  const float* src     = (const float*)d_in[0];
  const float* statc   = (const float*)d_in[1];
  const float* times   = (const float*)d_in[2];
  const int*   lengths = (const int*)  d_in[3];
  const float* R_u     = (const float*)d_in[4];
  const float* emb_w   = (const float*)d_in[5];
  const float* emb_b   = (const float*)d_in[6];
  const float* W1      = (const float*)d_in[7];
  const float* a1_s    = (const float*)d_in[8];
  const float* a1_d    = (const float*)d_in[9];
  const float* W2      = (const float*)d_in[10];
  const float* a2_s    = (const float*)d_in[11];
  const float* a2_d    = (const float*)d_in[12];
  const float* attn_in_w  = (const float*)d_in[13];
  const float* attn_in_b  = (const float*)d_in[14];
  const float* attn_out_w = (const float*)d_in[15];
  const float* attn_out_b = (const float*)d_in[16];
  const float* ff1_w = (const float*)d_in[17];
  const float* ff1_b = (const float*)d_in[18];
  const float* ff2_w = (const float*)d_in[19];
  const float* ff2_b = (const float*)d_in[20];
  const float* ln1_g = (const float*)d_in[21];
  const float* ln1_b = (const float*)d_in[22];
  const float* ln2_g = (const float*)d_in[23];
  const float* ln2_b = (const float*)d_in[24];
  const float* mlp1_w = (const float*)d_in[25];
  const float* mlp1_b = (const float*)d_in[26];
  const float* mlp2_w = (const float*)d_in[27];
  const float* mlp2_b = (const float*)d_in[28];

  // ---- small persistent buffers (floats) ----
  float* ws = (float*)d_ws;
  float* A1    = ws;                 // 663,552
  float* A2    = ws + 663552;        // 663,552
  float* SS    = ws + 1327104;       // 18,432
  float* SD    = ws + 1345536;       // 18,432
  float* SQB   = ws + 1363968;       // 512
  float* DSUM  = ws + 1364480;       // 64
  float* EMB   = ws + 1364544;       // 18,432
  float* FEAT  = ws + 1382976;       // 100,352
  float* FFEAT = ws + 1483328;       // 100,352
  const size_t CHBASE = 1583680;
  float* CH = ws + CHBASE;

  // ---- pick largest chunk size that fits ws_size ----
  // chunk area floats = XCH 34400*CB + max(GAT 92880*CB, TRANSF 199520*CB) = 233920*CB
  int CB = 8;
  const int cands[7] = {512, 256, 128, 64, 32, 16, 8};
  for (int c = 0; c < 7; ++c) {
    size_t need = 4ull * (CHBASE + 233920ull * (size_t)cands[c]);
    if (need <= ws_size) { CB = cands[c]; break; }
  }
  const int NCH = NB / CB;
  const int NTOKC = S_LEN * CB;

  // chunk-area views (floats, offsets from CH)
  float* XCH = CH;                         // 34,400*CB
  float* R0  = CH + (size_t)34400*CB;
  // GAT view
  float* Xc  = R0;                         // 30,960*CB
  float* XPc = R0 + (size_t)30960*CB;      // 30,960*CB
  float* H1c = R0 + (size_t)61920*CB;      // 30,960*CB
  // transformer view (GAT bufs dead)
  float* QKVc = R0;                        // 103,200*CB
  float* OAc  = R0 + (size_t)103200*CB;    // 34,400*CB
  float* Tc   = R0 + (size_t)137600*CB;    // 34,400*CB
  float* Yc   = R0 + (size_t)172000*CB;    // 27,520*CB

  hipMemsetAsync(DSUM, 0, 4, stream);
  zz_emb<<<dim3(CDIV(NB*DI,256)), 256, 0, stream>>>(statc, emb_w, emb_b, EMB);

  for (int ch = 0; ch < NCH; ++ch) {
    int b0 = ch * CB;
    // ---- GAT stack (chunk) ----
    zz_build_x<<<dim3(CDIV(CB*DI*S_LEN,256)), 256, 0, stream>>>(src, R_u, Xc, b0, CB);
    zz_gat_gemm<<<dim3(7, CB), 256, 0, stream>>>(Xc, W1, XPc);
    zz_gat_attvec<<<dim3(DI, CB), 64, 0, stream>>>(XPc, a1_s, a1_d, SS, SD, b0);
    zz_gat_alpha<<<dim3(CB), 256, 0, stream>>>(SS, SD, (const float*)nullptr, A1, b0);
    zz_gat_apply<<<dim3(7, CB), 256, 0, stream>>>(A1, XPc, H1c, 0, b0, CB);
    zz_gat_gemm<<<dim3(7, CB), 256, 0, stream>>>(H1c, W2, XPc);
    zz_gat_attvec<<<dim3(DI, CB), 64, 0, stream>>>(XPc, a2_s, a2_d, SS, SD, b0);
    zz_gat_alpha<<<dim3(CB), 256, 0, stream>>>(SS, SD, A1, A2, b0);
    zz_gat_apply<<<dim3(7, CB), 256, 0, stream>>>(A2, XPc, XCH, 1, b0, CB);
    zz_pe<<<dim3(CDIV(CB*S_LEN*16,256)), 256, 0, stream>>>(times, XCH, b0, CB);

    // ---- transformer (chunk) ----
    for (int l = 0; l < 2; ++l) {
      zz_gemm<0,0><<<dim3(CDIV(3*DT,64), CDIV(NTOKC,64)), 256, 0, stream>>>(XCH,
          attn_in_w + (size_t)l*DT*3*DT, attn_in_b + l*3*DT, nullptr, QKVc, NTOKC, 3*DT, DT);
      zz_attn<<<dim3(CB*NH), 256, 0, stream>>>(QKVc, lengths, OAc, b0, CB);
      zz_gemm<0,1><<<dim3(CDIV(DT,64), CDIV(NTOKC,64)), 256, 0, stream>>>(OAc,
          attn_out_w + (size_t)l*DT*DT, attn_out_b + l*DT, XCH, Tc, NTOKC, DT, DT);
      zz_ln<<<dim3(CDIV(NTOKC,4)), 256, 0, stream>>>(Tc, ln1_g + l*DT, ln1_b + l*DT, XCH, NTOKC);
      zz_gemm<1,0><<<dim3(CDIV(NHID,64), CDIV(NTOKC,64)), 256, 0, stream>>>(XCH,
          ff1_w + (size_t)l*DT*NHID, ff1_b + l*NHID, nullptr, Yc, NTOKC, NHID, DT);
      zz_gemm<0,1><<<dim3(CDIV(DT,64), CDIV(NTOKC,64)), 256, 0, stream>>>(Yc,
          ff2_w + (size_t)l*NHID*DT, ff2_b + l*DT, XCH, Tc, NTOKC, DT, NHID);
      zz_ln<<<dim3(CDIV(NTOKC,4)), 256, 0, stream>>>(Tc, ln2_g + l*DT, ln2_b + l*DT, XCH, NTOKC);
    }

    // ---- masked mean into FEAT rows b0..b0+CB ----
    zz_agg<<<dim3(CB), 256, 0, stream>>>(XCH, lengths, EMB, FEAT, b0, CB);
  }

  // ---- distance from alpha2 (full batch) ----
  zz_sq<<<dim3(NB), 64, 0, stream>>>(A2, SQB);
  zz_dist<<<dim3(8, 8), 256, 0, stream>>>(A2, SQB, DSUM);
  zz_dist_fin<<<1, 1, 0, stream>>>(DSUM, (float*)d_out + 1024);

  // ---- head ----
  zz_gemm<1,0><<<dim3(CDIV(DFIN,64), CDIV(NB,64)), 256, 0, stream>>>(FEAT, mlp1_w, mlp1_b,
      nullptr, FFEAT, NB, DFIN, DFIN);
  zz_gemm<0,0><<<dim3(1, CDIV(NB,64)), 256, 0, stream>>>(FFEAT, mlp2_w, mlp2_b,
      nullptr, (float*)d_out, NB, 2, DFIN);
}

// Round 4
// 6021.122 us; speedup vs baseline: 1.9026x; 1.9026x over previous
//
#include <hip/hip_runtime.h>
#include <math.h>

#define S_LEN 215
#define NB    512
#define DI    36
#define DMODEL 144
#define DT    160
#define NH    4
#define DH    40
#define NHID  128
#define FIN   860
#define DFIN  196
#define CDIV(a,b) (((a)+(b)-1)/(b))

// ---------------- build x chunk: Xc[bl,i,s*4+o] = relu(src[s,b0+bl,i] * R_u[i*4+o]) ----------------
__global__ __launch_bounds__(256) void zz_build_x(const float* __restrict__ src,
    const float* __restrict__ R_u, float* __restrict__ X, int b0, int CB)
{
  int idx = blockIdx.x*256 + threadIdx.x;           // (bl,i,s)
  if (idx >= CB*DI*S_LEN) return;
  int s = idx % S_LEN; int t = idx / S_LEN; int i = t % DI; int bl = t / DI;
  float v = src[((size_t)s*NB + b0 + bl)*(2*DI) + i];
  float4 r = *(const float4*)(R_u + i*4);
  float4 o;
  o.x = fmaxf(v*r.x, 0.f); o.y = fmaxf(v*r.y, 0.f);
  o.z = fmaxf(v*r.z, 0.f); o.w = fmaxf(v*r.w, 0.f);
  *(float4*)(X + (size_t)(bl*DI + i)*FIN + s*4) = o;
}

// ---------------- positional encoding into XCH cols 144..159 ----------------
__global__ __launch_bounds__(256) void zz_pe(const float* __restrict__ times,
    float* __restrict__ XCH, int b0, int CB)
{
  int idx = blockIdx.x*256 + threadIdx.x;           // (tl, k)
  if (idx >= CB*S_LEN*16) return;
  int k = idx & 15; int tl = idx >> 4;
  int bl = tl % CB; int s = tl / CB;
  int j = k & 7;
  float ts = powf(215.f, (float)j * (1.f/7.f)) * 100.f;
  float sc = times[(size_t)s*NB + b0 + bl] / ts;
  XCH[(size_t)tl*DT + DMODEL + k] = (k < 8) ? sinf(sc) : cosf(sc);
}

// ---------------- emb = static @ emb_w + emb_b ----------------
__global__ __launch_bounds__(256) void zz_emb(const float* __restrict__ st,
    const float* __restrict__ w, const float* __restrict__ bias, float* __restrict__ emb)
{
  int idx = blockIdx.x*256 + threadIdx.x;
  if (idx >= NB*DI) return;
  int b = idx / DI, k = idx % DI;
  float acc = bias[k];
  #pragma unroll
  for (int j = 0; j < 9; ++j) acc = fmaf(st[b*9 + j], w[j*DI + k], acc);
  emb[idx] = acc;
}

// ---------------- per-sample GEMM: XP[bl] = Xin[bl](36x860) @ W(860x860) ----------------
// 256 threads = 4 m-groups(9 rows) x 64 n-threads(4 cols) ; n-tile = 256
__global__ __launch_bounds__(256) void zz_gat_gemm(const float* __restrict__ Xin,
    const float* __restrict__ W, float* __restrict__ XP)
{
  __shared__ float As[DI][33];     // [m][kk]  (broadcast reads)
  __shared__ float Ws[32][260];    // [kk][n]  row = 1040B, 16B-aligned
  int bl = blockIdx.y, n0 = blockIdx.x * 256;
  int tid = threadIdx.x;
  int nt = tid & 63, mg = tid >> 6;    // mg in 0..3 (wave-uniform)
  const float* Xb = Xin + (size_t)bl*DI*FIN;
  float acc[9][4] = {};
  for (int k0 = 0; k0 < FIN; k0 += 32) {
    for (int i = tid; i < DI*32; i += 256) {
      int m = i >> 5, kk = i & 31, gk = k0 + kk;
      As[m][kk] = (gk < FIN) ? Xb[m*FIN + gk] : 0.f;
    }
    for (int i = tid; i < 32*256; i += 256) {
      int kk = i >> 8, nn = i & 255;
      int gk = k0 + kk, gn = n0 + nn;
      Ws[kk][nn] = (gk < FIN && gn < FIN) ? W[(size_t)gk*FIN + gn] : 0.f;
    }
    __syncthreads();
    #pragma unroll 4
    for (int kk = 0; kk < 32; ++kk) {
      float4 w4 = *(const float4*)&Ws[kk][nt*4];
      float wb[4] = {w4.x, w4.y, w4.z, w4.w};
      #pragma unroll
      for (int m = 0; m < 9; ++m) {
        float av = As[mg*9 + m][kk];
        #pragma unroll
        for (int v = 0; v < 4; ++v) acc[m][v] = fmaf(av, wb[v], acc[m][v]);
      }
    }
    __syncthreads();
  }
  int gn = n0 + nt*4;
  if (gn < FIN) {
    float* XPb = XP + (size_t)bl*DI*FIN;
    #pragma unroll
    for (int m = 0; m < 9; ++m) {
      float4 o4 = {acc[m][0], acc[m][1], acc[m][2], acc[m][3]};
      *(float4*)(XPb + (mg*9 + m)*FIN + gn) = o4;
    }
  }
}

// ---------------- per-row dots: ss=xp·a_s, sd=xp·a_d ----------------
__global__ __launch_bounds__(64) void zz_gat_attvec(const float* __restrict__ XP,
    const float* __restrict__ a_s, const float* __restrict__ a_d,
    float* __restrict__ ss, float* __restrict__ sd, int b0)
{
  int i = blockIdx.x, bl = blockIdx.y, lane = threadIdx.x;
  const float* row = XP + ((size_t)bl*DI + i)*FIN;
  float ps = 0.f, pd = 0.f;
  for (int k = lane; k < FIN; k += 64) {
    float v = row[k];
    ps = fmaf(v, a_s[k], ps);
    pd = fmaf(v, a_d[k], pd);
  }
  for (int off = 32; off; off >>= 1) { ps += __shfl_xor(ps, off); pd += __shfl_xor(pd, off); }
  if (!lane) { ss[(b0 + bl)*DI + i] = ps; sd[(b0 + bl)*DI + i] = pd; }
}

// ---------------- alpha[b,i,j] = softmax_j(lrelu(sd_i + ss_j)) * edge ----------------
__global__ __launch_bounds__(256) void zz_gat_alpha(const float* __restrict__ ss,
    const float* __restrict__ sd, const float* __restrict__ edge, float* __restrict__ alpha, int b0)
{
  int b = b0 + blockIdx.x;
  int wv = threadIdx.x >> 6, lane = threadIdx.x & 63;
  for (int i = wv; i < DI; i += 4) {
    float di = sd[b*DI + i];
    float e = -3e38f, x = 0.f;
    if (lane < DI) {
      x = di + ss[b*DI + lane];
      x = (x >= 0.f) ? x : 0.2f*x;
      e = x;
    }
    float m = e;
    for (int off = 32; off; off >>= 1) m = fmaxf(m, __shfl_xor(m, off));
    float p = (lane < DI) ? expf(e - m) : 0.f;
    float s = p;
    for (int off = 32; off; off >>= 1) s += __shfl_xor(s, off);
    if (lane < DI) {
      float a = p / s;
      size_t o = ((size_t)b*DI + i)*DI + lane;
      if (edge) a *= edge[o];
      alpha[o] = a;
    }
  }
}

// ---------------- h[bl] = alpha[b](36x36) @ XP[bl](36x860); mode1 scatters to XCH ----------------
__global__ __launch_bounds__(256) void zz_gat_apply(const float* __restrict__ alpha,
    const float* __restrict__ XP, float* __restrict__ out, int mode, int b0, int CB)
{
  __shared__ float Al[DI][37];
  __shared__ float Xs[DI][260];
  int bl = blockIdx.y, n0 = blockIdx.x * 256;
  int tid = threadIdx.x;
  int nt = tid & 63, mg = tid >> 6;
  const float* ab = alpha + ((size_t)(b0 + bl))*DI*DI;
  for (int i = tid; i < DI*DI; i += 256) Al[i/DI][i%DI] = ab[i];
  const float* XPb = XP + (size_t)bl*DI*FIN;
  for (int i = tid; i < DI*256; i += 256) {
    int k = i >> 8, nn = i & 255, gn = n0 + nn;
    Xs[k][nn] = (gn < FIN) ? XPb[k*FIN + gn] : 0.f;
  }
  __syncthreads();
  float acc[9][4] = {};
  #pragma unroll 4
  for (int k = 0; k < DI; ++k) {
    float4 x4 = *(const float4*)&Xs[k][nt*4];
    float xb[4] = {x4.x, x4.y, x4.z, x4.w};
    #pragma unroll
    for (int m = 0; m < 9; ++m) {
      float av = Al[mg*9 + m][k];
      #pragma unroll
      for (int v = 0; v < 4; ++v) acc[m][v] = fmaf(av, xb[v], acc[m][v]);
    }
  }
  int gn = n0 + nt*4;
  if (gn < FIN) {
    if (mode == 0) {
      float* ob = out + (size_t)bl*DI*FIN;
      #pragma unroll
      for (int m = 0; m < 9; ++m) {
        float4 o4 = {acc[m][0], acc[m][1], acc[m][2], acc[m][3]};
        *(float4*)(ob + (mg*9 + m)*FIN + gn) = o4;
      }
    } else {
      int s = gn >> 2;            // gn = s*4 + o, o = 0..3 = v
      float* op = out + ((size_t)s*CB + bl)*DT;
      #pragma unroll
      for (int m = 0; m < 9; ++m) {
        float4 o4 = {acc[m][0], acc[m][1], acc[m][2], acc[m][3]};
        *(float4*)(op + (mg*9 + m)*4) = o4;   // channel (mg*9+m)*4 + o
      }
    }
  }
}

// ---------------- distance helpers ----------------
__global__ __launch_bounds__(64) void zz_sq(const float* __restrict__ A, float* __restrict__ sq)
{
  int i = blockIdx.x, lane = threadIdx.x;
  const float* row = A + (size_t)i*(DI*DI);
  float s = 0.f;
  for (int k = lane; k < DI*DI; k += 64) { float v = row[k]; s = fmaf(v, v, s); }
  for (int off = 32; off; off >>= 1) s += __shfl_xor(s, off);
  if (!lane) sq[i] = s;
}

__global__ __launch_bounds__(256) void zz_dist(const float* __restrict__ A,
    const float* __restrict__ sq, float* __restrict__ dsum)
{
  __shared__ float Ai[64][65], Aj[64][65];
  __shared__ float red[256];
  int i0 = blockIdx.y*64, j0 = blockIdx.x*64;
  int tid = threadIdx.x, tx = tid % 16, ty = tid / 16;
  float acc[4][4] = {};
  for (int k0 = 0; k0 < DI*DI; k0 += 64) {
    for (int t = tid; t < 64*64; t += 256) {
      int r = t >> 6, kk = t & 63, gk = k0 + kk;
      float vi = 0.f, vj = 0.f;
      if (gk < DI*DI) {
        vi = A[(size_t)(i0 + r)*(DI*DI) + gk];
        vj = A[(size_t)(j0 + r)*(DI*DI) + gk];
      }
      Ai[r][kk] = vi; Aj[r][kk] = vj;
    }
    __syncthreads();
    #pragma unroll 8
    for (int kk = 0; kk < 64; ++kk) {
      float a[4], bb[4];
      #pragma unroll
      for (int u = 0; u < 4; ++u) a[u]  = Ai[ty*4 + u][kk];
      #pragma unroll
      for (int u = 0; u < 4; ++u) bb[u] = Aj[tx*4 + u][kk];
      #pragma unroll
      for (int u = 0; u < 4; ++u)
        #pragma unroll
        for (int v = 0; v < 4; ++v) acc[u][v] = fmaf(a[u], bb[v], acc[u][v]);
    }
    __syncthreads();
  }
  float s = 0.f;
  #pragma unroll
  for (int u = 0; u < 4; ++u)
    #pragma unroll
    for (int v = 0; v < 4; ++v) {
      float d2 = sq[i0 + ty*4 + u] + sq[j0 + tx*4 + v] - 2.f*acc[u][v];
      d2 = fmaxf(d2, 0.f);
      s += sqrtf(d2 + 1e-12f);
    }
  red[tid] = s; __syncthreads();
  for (int st = 128; st; st >>= 1) { if (tid < st) red[tid] += red[tid + st]; __syncthreads(); }
  if (!tid) atomicAdd(dsum, red[0]);
}

__global__ void zz_dist_fin(const float* dsum, float* out)
{
  out[0] = dsum[0] * (1.f/((float)NB*(float)NB));
}

// ---------------- tiled f32 GEMM: 64x128 tile, 4x8 micro ----------------
template<int RELU, int RES>
__global__ __launch_bounds__(256) void zz_gemm(const float* __restrict__ A,
    const float* __restrict__ Bw, const float* __restrict__ bias,
    const float* __restrict__ res, float* __restrict__ C, int M, int N, int K)
{
  __shared__ float As[64][33];     // [m][kk]  broadcast reads
  __shared__ float Bs[32][136];    // [kk][n]  row 544B, 16B-aligned
  int m0 = blockIdx.y*64, n0 = blockIdx.x*128;
  int tid = threadIdx.x, tx = tid & 15, ty = tid >> 4;   // ty: 4 rows, tx: 8 cols
  float acc[4][8] = {};
  for (int k0 = 0; k0 < K; k0 += 32) {
    for (int i = tid; i < 64*32; i += 256) {
      int r = i >> 5, kk = i & 31;
      int gm = m0 + r, gk = k0 + kk;
      As[r][kk] = (gm < M && gk < K) ? A[(size_t)gm*K + gk] : 0.f;
    }
    for (int i = tid; i < 32*128; i += 256) {
      int kk = i >> 7, n = i & 127;
      int gk = k0 + kk, gn = n0 + n;
      Bs[kk][n] = (gk < K && gn < N) ? Bw[(size_t)gk*N + gn] : 0.f;
    }
    __syncthreads();
    #pragma unroll 4
    for (int kk = 0; kk < 32; ++kk) {
      float a[4];
      #pragma unroll
      for (int u = 0; u < 4; ++u) a[u] = As[ty*4 + u][kk];
      float4 b0 = *(const float4*)&Bs[kk][tx*8];
      float4 b1 = *(const float4*)&Bs[kk][tx*8 + 4];
      float b[8] = {b0.x,b0.y,b0.z,b0.w,b1.x,b1.y,b1.z,b1.w};
      #pragma unroll
      for (int u = 0; u < 4; ++u)
        #pragma unroll
        for (int v = 0; v < 8; ++v) acc[u][v] = fmaf(a[u], b[v], acc[u][v]);
    }
    __syncthreads();
  }
  #pragma unroll
  for (int u = 0; u < 4; ++u) {
    int gm = m0 + ty*4 + u;
    if (gm >= M) continue;
    #pragma unroll
    for (int v = 0; v < 8; ++v) {
      int gn = n0 + tx*8 + v;
      if (gn >= N) continue;
      float val = acc[u][v] + bias[gn];
      if (RES) val += res[(size_t)gm*N + gn];
      if (RELU) val = fmaxf(val, 0.f);
      C[(size_t)gm*N + gn] = val;
    }
  }
}

// ---------------- attention: block per (bl,h); one thread = one query; no inner barriers ----------------
__global__ __launch_bounds__(256) void zz_attn(const float* __restrict__ QKV,
    const int* __restrict__ lengths, float* __restrict__ O, int b0, int CB)
{
  __shared__ float Kl[S_LEN][DH+1];
  __shared__ float Vl[S_LEN][DH+1];
  int bl = blockIdx.x >> 2, h = blockIdx.x & 3;
  int tid = threadIdx.x;
  int len = lengths[b0 + bl];
  for (int i = tid; i < S_LEN*DH; i += 256) {
    int s = i / DH, d = i - s*DH;
    const float* base = QKV + ((size_t)s*CB + bl)*(3*DT) + h*DH + d;
    Kl[s][d] = base[DT];
    Vl[s][d] = base[2*DT];
  }
  __syncthreads();
  if (tid >= S_LEN) return;
  // my query row (16B-aligned)
  float q[DH];
  const float* qp = QKV + ((size_t)tid*CB + bl)*(3*DT) + h*DH;
  #pragma unroll
  for (int d = 0; d < DH; d += 4) {
    float4 t4 = *(const float4*)(qp + d);
    q[d] = t4.x; q[d+1] = t4.y; q[d+2] = t4.z; q[d+3] = t4.w;
  }
  // online softmax over keys 0..len-1 (masked keys contribute exactly 0)
  float m = -3e38f, l = 0.f;
  float o[DH] = {};
  for (int t = 0; t < len; ++t) {
    float sc = 0.f;
    #pragma unroll
    for (int d = 0; d < DH; ++d) sc = fmaf(q[d], Kl[t][d], sc);   // broadcast reads
    sc *= 0.15811388300841897f;
    float mn = fmaxf(m, sc);
    float corr = exp2f((m - mn) * 1.44269504088896f);
    float p    = exp2f((sc - mn) * 1.44269504088896f);
    l = l*corr + p;
    #pragma unroll
    for (int d = 0; d < DH; ++d) o[d] = fmaf(p, Vl[t][d], o[d]*corr);
    m = mn;
  }
  float inv = 1.f / l;
  float* op = O + ((size_t)tid*CB + bl)*DT + h*DH;
  #pragma unroll
  for (int d = 0; d < DH; d += 4) {
    float4 o4 = {o[d]*inv, o[d+1]*inv, o[d+2]*inv, o[d+3]*inv};
    *(float4*)(op + d) = o4;
  }
}

// ---------------- layernorm over 160, one wave per token ----------------
__global__ __launch_bounds__(256) void zz_ln(const float* __restrict__ X,
    const float* __restrict__ g, const float* __restrict__ bt, float* __restrict__ Y, int ntok)
{
  int tok = blockIdx.x*4 + (threadIdx.x >> 6);
  if (tok >= ntok) return;
  int lane = threadIdx.x & 63;
  const float* x = X + (size_t)tok*DT;
  float v0 = x[lane], v1 = x[lane + 64];
  float v2 = (lane < 32) ? x[lane + 128] : 0.f;
  float s = v0 + v1 + v2;
  for (int off = 32; off; off >>= 1) s += __shfl_xor(s, off);
  float mean = s * (1.f/160.f);
  float d0 = v0 - mean, d1 = v1 - mean, d2 = (lane < 32) ? (v2 - mean) : 0.f;
  float q = d0*d0 + d1*d1 + d2*d2;
  for (int off = 32; off; off >>= 1) q += __shfl_xor(q, off);
  float inv = 1.f / sqrtf(q * (1.f/160.f) + 1e-5f);
  float* y = Y + (size_t)tok*DT;
  y[lane]      = d0*inv*g[lane]      + bt[lane];
  y[lane + 64] = d1*inv*g[lane + 64] + bt[lane + 64];
  if (lane < 32) y[lane + 128] = d2*inv*g[lane + 128] + bt[lane + 128];
}

// ---------------- masked mean + feat concat ----------------
__global__ __launch_bounds__(256) void zz_agg(const float* __restrict__ XCH,
    const int* __restrict__ lengths, const float* __restrict__ emb, float* __restrict__ feat,
    int b0, int CB)
{
  int bl = blockIdx.x, tid = threadIdx.x;
  int b = b0 + bl;
  int len = lengths[b];
  if (tid < DT) {
    float acc = 0.f;
    for (int s = 0; s < len; ++s) acc += XCH[((size_t)s*CB + bl)*DT + tid];
    feat[(size_t)b*DFIN + tid] = acc / (float)(len + 1);
  } else if (tid < DFIN) {
    feat[(size_t)b*DFIN + tid] = emb[b*DI + (tid - DT)];
  }
}

// ======================================================================
extern "C" void kernel_launch(void* const* d_in, const int* in_sizes, int n_in,
                              void* d_out, int out_size, void* d_ws, size_t ws_size,
                              hipStream_t stream)
{
  (void)in_sizes; (void)n_in; (void)out_size;
  const float* src     = (const float*)d_in[0];
  const float* statc   = (const float*)d_in[1];
  const float* times   = (const float*)d_in[2];
  const int*   lengths = (const int*)  d_in[3];
  const float* R_u     = (const float*)d_in[4];
  const float* emb_w   = (const float*)d_in[5];
  const float* emb_b   = (const float*)d_in[6];
  const float* W1      = (const float*)d_in[7];
  const float* a1_s    = (const float*)d_in[8];
  const float* a1_d    = (const float*)d_in[9];
  const float* W2      = (const float*)d_in[10];
  const float* a2_s    = (const float*)d_in[11];
  const float* a2_d    = (const float*)d_in[12];
  const float* attn_in_w  = (const float*)d_in[13];
  const float* attn_in_b  = (const float*)d_in[14];
  const float* attn_out_w = (const float*)d_in[15];
  const float* attn_out_b = (const float*)d_in[16];
  const float* ff1_w = (const float*)d_in[17];
  const float* ff1_b = (const float*)d_in[18];
  const float* ff2_w = (const float*)d_in[19];
  const float* ff2_b = (const float*)d_in[20];
  const float* ln1_g = (const float*)d_in[21];
  const float* ln1_b = (const float*)d_in[22];
  const float* ln2_g = (const float*)d_in[23];
  const float* ln2_b = (const float*)d_in[24];
  const float* mlp1_w = (const float*)d_in[25];
  const float* mlp1_b = (const float*)d_in[26];
  const float* mlp2_w = (const float*)d_in[27];
  const float* mlp2_b = (const float*)d_in[28];

  // ---- small persistent buffers (floats) ----
  float* ws = (float*)d_ws;
  float* A1    = ws;                 // 663,552
  float* A2    = ws + 663552;        // 663,552
  float* SS    = ws + 1327104;       // 18,432
  float* SD    = ws + 1345536;       // 18,432
  float* SQB   = ws + 1363968;       // 512
  float* DSUM  = ws + 1364480;       // 64
  float* EMB   = ws + 1364544;       // 18,432
  float* FEAT  = ws + 1382976;       // 100,352
  float* FFEAT = ws + 1483328;       // 100,352
  const size_t CHBASE = 1583680;
  float* CH = ws + CHBASE;

  // ---- pick largest chunk size that fits ws_size ----
  int CB = 8;
  const int cands[7] = {512, 256, 128, 64, 32, 16, 8};
  for (int c = 0; c < 7; ++c) {
    size_t need = 4ull * (CHBASE + 233920ull * (size_t)cands[c]);
    if (need <= ws_size) { CB = cands[c]; break; }
  }
  const int NCH = NB / CB;
  const int NTOKC = S_LEN * CB;

  // chunk-area views (floats, offsets from CH)
  float* XCH = CH;                         // 34,400*CB
  float* R0  = CH + (size_t)34400*CB;
  // GAT view
  float* Xc  = R0;                         // 30,960*CB
  float* XPc = R0 + (size_t)30960*CB;      // 30,960*CB
  float* H1c = R0 + (size_t)61920*CB;      // 30,960*CB
  // transformer view (GAT bufs dead)
  float* QKVc = R0;                        // 103,200*CB
  float* OAc  = R0 + (size_t)103200*CB;    // 34,400*CB
  float* Tc   = R0 + (size_t)137600*CB;    // 34,400*CB
  float* Yc   = R0 + (size_t)172000*CB;    // 27,520*CB

  hipMemsetAsync(DSUM, 0, 4, stream);
  zz_emb<<<dim3(CDIV(NB*DI,256)), 256, 0, stream>>>(statc, emb_w, emb_b, EMB);

  for (int ch = 0; ch < NCH; ++ch) {
    int b0 = ch * CB;
    // ---- GAT stack (chunk) ----
    zz_build_x<<<dim3(CDIV(CB*DI*S_LEN,256)), 256, 0, stream>>>(src, R_u, Xc, b0, CB);
    zz_gat_gemm<<<dim3(4, CB), 256, 0, stream>>>(Xc, W1, XPc);
    zz_gat_attvec<<<dim3(DI, CB), 64, 0, stream>>>(XPc, a1_s, a1_d, SS, SD, b0);
    zz_gat_alpha<<<dim3(CB), 256, 0, stream>>>(SS, SD, (const float*)nullptr, A1, b0);
    zz_gat_apply<<<dim3(4, CB), 256, 0, stream>>>(A1, XPc, H1c, 0, b0, CB);
    zz_gat_gemm<<<dim3(4, CB), 256, 0, stream>>>(H1c, W2, XPc);
    zz_gat_attvec<<<dim3(DI, CB), 64, 0, stream>>>(XPc, a2_s, a2_d, SS, SD, b0);
    zz_gat_alpha<<<dim3(CB), 256, 0, stream>>>(SS, SD, A1, A2, b0);
    zz_gat_apply<<<dim3(4, CB), 256, 0, stream>>>(A2, XPc, XCH, 1, b0, CB);
    zz_pe<<<dim3(CDIV(CB*S_LEN*16,256)), 256, 0, stream>>>(times, XCH, b0, CB);

    // ---- transformer (chunk) ----
    for (int l = 0; l < 2; ++l) {
      zz_gemm<0,0><<<dim3(CDIV(3*DT,128), CDIV(NTOKC,64)), 256, 0, stream>>>(XCH,
          attn_in_w + (size_t)l*DT*3*DT, attn_in_b + l*3*DT, nullptr, QKVc, NTOKC, 3*DT, DT);
      zz_attn<<<dim3(CB*NH), 256, 0, stream>>>(QKVc, lengths, OAc, b0, CB);
      zz_gemm<0,1><<<dim3(CDIV(DT,128), CDIV(NTOKC,64)), 256, 0, stream>>>(OAc,
          attn_out_w + (size_t)l*DT*DT, attn_out_b + l*DT, XCH, Tc, NTOKC, DT, DT);
      zz_ln<<<dim3(CDIV(NTOKC,4)), 256, 0, stream>>>(Tc, ln1_g + l*DT, ln1_b + l*DT, XCH, NTOKC);
      zz_gemm<1,0><<<dim3(CDIV(NHID,128), CDIV(NTOKC,64)), 256, 0, stream>>>(XCH,
          ff1_w + (size_t)l*DT*NHID, ff1_b + l*NHID, nullptr, Yc, NTOKC, NHID, DT);
      zz_gemm<0,1><<<dim3(CDIV(DT,128), CDIV(NTOKC,64)), 256, 0, stream>>>(Yc,
          ff2_w + (size_t)l*NHID*DT, ff2_b + l*DT, XCH, Tc, NTOKC, DT, NHID);
      zz_ln<<<dim3(CDIV(NTOKC,4)), 256, 0, stream>>>(Tc, ln2_g + l*DT, ln2_b + l*DT, XCH, NTOKC);
    }

    // ---- masked mean into FEAT rows b0..b0+CB ----
    zz_agg<<<dim3(CB), 256, 0, stream>>>(XCH, lengths, EMB, FEAT, b0, CB);
  }

  // ---- distance from alpha2 (full batch) ----
  zz_sq<<<dim3(NB), 64, 0, stream>>>(A2, SQB);
  zz_dist<<<dim3(8, 8), 256, 0, stream>>>(A2, SQB, DSUM);
  zz_dist_fin<<<1, 1, 0, stream>>>(DSUM, (float*)d_out + 1024);

  // ---- head ----
  zz_gemm<1,0><<<dim3(CDIV(DFIN,128), CDIV(NB,64)), 256, 0, stream>>>(FEAT, mlp1_w, mlp1_b,
      nullptr, FFEAT, NB, DFIN, DFIN);
  zz_gemm<0,0><<<dim3(1, CDIV(NB,64)), 256, 0, stream>>>(FFEAT, mlp2_w, mlp2_b,
      nullptr, (float*)d_out, NB, 2, DFIN);
}

// Round 5
// 3600.245 us; speedup vs baseline: 3.1820x; 1.6724x over previous
//
#include <hip/hip_runtime.h>
#include <hip/hip_bf16.h>
#include <math.h>

#define S_LEN 215
#define NB    512
#define DI    36
#define DMODEL 144
#define DT    160
#define NH    4
#define DH    40
#define NHID  128
#define FIN   860
#define FINP  864          // K-padded
#define DFIN  196
#define CDIV(a,b) (((a)+(b)-1)/(b))

typedef __attribute__((ext_vector_type(8))) short bf16x8;
typedef __attribute__((ext_vector_type(4))) float f32x4;

__device__ inline bf16x8 zz_cvt8(const float* __restrict__ p) {
  float4 lo = *(const float4*)p;
  float4 hi = *(const float4*)(p + 4);
  union { bf16x8 v; __hip_bfloat16 h[8]; } u;
  u.h[0] = __float2bfloat16(lo.x); u.h[1] = __float2bfloat16(lo.y);
  u.h[2] = __float2bfloat16(lo.z); u.h[3] = __float2bfloat16(lo.w);
  u.h[4] = __float2bfloat16(hi.x); u.h[5] = __float2bfloat16(hi.y);
  u.h[6] = __float2bfloat16(hi.z); u.h[7] = __float2bfloat16(hi.w);
  return u.v;
}

// ---------------- weight transpose + bf16 convert: WT[n][k] = bf16(W[k][n]) ----------------
__global__ __launch_bounds__(256) void zz_wcvt(const float* __restrict__ W,
    short* __restrict__ WT, int K, int N, int Kpad, int Npad)
{
  int idx = blockIdx.x*256 + threadIdx.x;
  if (idx >= Npad*Kpad) return;
  int n = idx / Kpad, k = idx % Kpad;
  float v = (n < N && k < K) ? W[(size_t)k*N + n] : 0.f;
  union { __hip_bfloat16 h; short s; } c;
  c.h = __float2bfloat16(v);
  WT[idx] = c.s;
}

// ---------------- build x chunk: Xc[bl,i,s*4+o] = relu(src[s,b0+bl,i]*R_u[i*4+o]), stride FINP ----------------
__global__ __launch_bounds__(256) void zz_build_x(const float* __restrict__ src,
    const float* __restrict__ R_u, float* __restrict__ X, int b0, int CB)
{
  int idx = blockIdx.x*256 + threadIdx.x;           // (bl,i,s)
  if (idx >= CB*DI*S_LEN) return;
  int s = idx % S_LEN; int t = idx / S_LEN; int i = t % DI; int bl = t / DI;
  float v = src[((size_t)s*NB + b0 + bl)*(2*DI) + i];
  float4 r = *(const float4*)(R_u + i*4);
  float4 o;
  o.x = fmaxf(v*r.x, 0.f); o.y = fmaxf(v*r.y, 0.f);
  o.z = fmaxf(v*r.z, 0.f); o.w = fmaxf(v*r.w, 0.f);
  *(float4*)(X + (size_t)(bl*DI + i)*FINP + s*4) = o;
}

// ---------------- zero pad cols 860..863 of a [CB*36][864] buffer ----------------
__global__ __launch_bounds__(256) void zz_zeropad(float* __restrict__ buf, int CB)
{
  int idx = blockIdx.x*256 + threadIdx.x;
  if (idx >= CB*DI) return;
  float4 z = {0.f,0.f,0.f,0.f};
  *(float4*)(buf + (size_t)idx*FINP + FIN) = z;
}

// ---------------- positional encoding into XCH cols 144..159 ----------------
__global__ __launch_bounds__(256) void zz_pe(const float* __restrict__ times,
    float* __restrict__ XCH, int b0, int CB)
{
  int idx = blockIdx.x*256 + threadIdx.x;           // (tl, k)
  if (idx >= CB*S_LEN*16) return;
  int k = idx & 15; int tl = idx >> 4;
  int bl = tl % CB; int s = tl / CB;
  int j = k & 7;
  float ts = powf(215.f, (float)j * (1.f/7.f)) * 100.f;
  float sc = times[(size_t)s*NB + b0 + bl] / ts;
  XCH[(size_t)tl*DT + DMODEL + k] = (k < 8) ? sinf(sc) : cosf(sc);
}

// ---------------- emb = static @ emb_w + emb_b ----------------
__global__ __launch_bounds__(256) void zz_emb(const float* __restrict__ st,
    const float* __restrict__ w, const float* __restrict__ bias, float* __restrict__ emb)
{
  int idx = blockIdx.x*256 + threadIdx.x;
  if (idx >= NB*DI) return;
  int b = idx / DI, k = idx % DI;
  float acc = bias[k];
  #pragma unroll
  for (int j = 0; j < 9; ++j) acc = fmaf(st[b*9 + j], w[j*DI + k], acc);
  emb[idx] = acc;
}

// ---------------- GAT GEMM via MFMA: XP[bl](36x860,s864) = X[bl](36x864) @ W(864x864 bf16 WT) ----------------
// block = 256 thr (4 waves) per (half, sample); wave loops tasks (mt, ntp-pair)
__global__ __launch_bounds__(256) void zz_gat_mfma(const float* __restrict__ X,
    const short* __restrict__ WT, float* __restrict__ XP, int CB)
{
  int bl = blockIdx.y, half = blockIdx.x;
  int wave = threadIdx.x >> 6, lane = threadIdx.x & 63;
  int r = lane & 15, g = lane >> 4;
  const float* Xb = X + (size_t)bl*DI*FINP;
  float* XPb = XP + (size_t)bl*DI*FINP;
  int p0 = half ? 14 : 0, p1 = half ? 27 : 14;   // 27 n-pairs of 32 cols
  int ntasks = 3 * (p1 - p0);
  for (int task = wave; task < ntasks; task += 4) {
    int mt = task % 3; int ntp = p0 + task / 3;
    int m0 = mt*16;
    int arow = m0 + r; if (arow > DI-1) arow = DI-1;
    const float* Ap = Xb + (size_t)arow*FINP + g*8;
    int n0 = ntp*32;
    const short* B0 = WT + (size_t)(n0 + r)*FINP + g*8;
    const short* B1 = B0 + (size_t)16*FINP;
    f32x4 acc0 = {0.f,0.f,0.f,0.f}, acc1 = {0.f,0.f,0.f,0.f};
    #pragma unroll 3
    for (int k0 = 0; k0 < FINP; k0 += 32) {
      bf16x8 af = zz_cvt8(Ap + k0);
      bf16x8 b0 = *(const bf16x8*)(B0 + k0);
      bf16x8 b1 = *(const bf16x8*)(B1 + k0);
      acc0 = __builtin_amdgcn_mfma_f32_16x16x32_bf16(af, b0, acc0, 0, 0, 0);
      acc1 = __builtin_amdgcn_mfma_f32_16x16x32_bf16(af, b1, acc1, 0, 0, 0);
    }
    #pragma unroll
    for (int j = 0; j < 4; ++j) {
      int row = m0 + g*4 + j;
      if (row < DI) {
        int c0 = n0 + r, c1 = n0 + 16 + r;
        if (c0 < FIN) XPb[(size_t)row*FINP + c0] = acc0[j];
        if (c1 < FIN) XPb[(size_t)row*FINP + c1] = acc1[j];
      }
    }
  }
}

// ---------------- per-row dots: ss=xp·a_s, sd=xp·a_d (XP stride FINP) ----------------
__global__ __launch_bounds__(64) void zz_gat_attvec(const float* __restrict__ XP,
    const float* __restrict__ a_s, const float* __restrict__ a_d,
    float* __restrict__ ss, float* __restrict__ sd, int b0)
{
  int i = blockIdx.x, bl = blockIdx.y, lane = threadIdx.x;
  const float* row = XP + ((size_t)bl*DI + i)*FINP;
  float ps = 0.f, pd = 0.f;
  for (int k = lane; k < FIN; k += 64) {
    float v = row[k];
    ps = fmaf(v, a_s[k], ps);
    pd = fmaf(v, a_d[k], pd);
  }
  for (int off = 32; off; off >>= 1) { ps += __shfl_xor(ps, off); pd += __shfl_xor(pd, off); }
  if (!lane) { ss[(b0 + bl)*DI + i] = ps; sd[(b0 + bl)*DI + i] = pd; }
}

// ---------------- alpha[b,i,j] = softmax_j(lrelu(sd_i + ss_j)) * edge ----------------
__global__ __launch_bounds__(256) void zz_gat_alpha(const float* __restrict__ ss,
    const float* __restrict__ sd, const float* __restrict__ edge, float* __restrict__ alpha, int b0)
{
  int b = b0 + blockIdx.x;
  int wv = threadIdx.x >> 6, lane = threadIdx.x & 63;
  for (int i = wv; i < DI; i += 4) {
    float di = sd[b*DI + i];
    float e = -3e38f, x = 0.f;
    if (lane < DI) {
      x = di + ss[b*DI + lane];
      x = (x >= 0.f) ? x : 0.2f*x;
      e = x;
    }
    float m = e;
    for (int off = 32; off; off >>= 1) m = fmaxf(m, __shfl_xor(m, off));
    float p = (lane < DI) ? expf(e - m) : 0.f;
    float s = p;
    for (int off = 32; off; off >>= 1) s += __shfl_xor(s, off);
    if (lane < DI) {
      float a = p / s;
      size_t o = ((size_t)b*DI + i)*DI + lane;
      if (edge) a *= edge[o];
      alpha[o] = a;
    }
  }
}

// ---------------- h[bl] = alpha[b](36x36) @ XP[bl](36x860,s864); mode1 -> XCH ----------------
__global__ __launch_bounds__(256) void zz_gat_apply(const float* __restrict__ alpha,
    const float* __restrict__ XP, float* __restrict__ out, int mode, int b0, int CB)
{
  __shared__ float Al[DI][37];
  __shared__ float Xs[DI][260];
  int bl = blockIdx.y, n0 = blockIdx.x * 256;
  int tid = threadIdx.x;
  int nt = tid & 63, mg = tid >> 6;
  const float* ab = alpha + ((size_t)(b0 + bl))*DI*DI;
  for (int i = tid; i < DI*DI; i += 256) Al[i/DI][i%DI] = ab[i];
  const float* XPb = XP + (size_t)bl*DI*FINP;
  for (int i = tid; i < DI*256; i += 256) {
    int k = i >> 8, nn = i & 255, gn = n0 + nn;
    Xs[k][nn] = (gn < FIN) ? XPb[(size_t)k*FINP + gn] : 0.f;
  }
  __syncthreads();
  float acc[9][4] = {};
  #pragma unroll 4
  for (int k = 0; k < DI; ++k) {
    float4 x4 = *(const float4*)&Xs[k][nt*4];
    float xb[4] = {x4.x, x4.y, x4.z, x4.w};
    #pragma unroll
    for (int m = 0; m < 9; ++m) {
      float av = Al[mg*9 + m][k];
      #pragma unroll
      for (int v = 0; v < 4; ++v) acc[m][v] = fmaf(av, xb[v], acc[m][v]);
    }
  }
  int gn = n0 + nt*4;
  if (gn < FIN) {
    if (mode == 0) {
      float* ob = out + (size_t)bl*DI*FINP;
      #pragma unroll
      for (int m = 0; m < 9; ++m) {
        float4 o4 = {acc[m][0], acc[m][1], acc[m][2], acc[m][3]};
        *(float4*)(ob + (size_t)(mg*9 + m)*FINP + gn) = o4;
      }
    } else {
      int s = gn >> 2;
      float* op = out + ((size_t)s*CB + bl)*DT;
      #pragma unroll
      for (int m = 0; m < 9; ++m) {
        float4 o4 = {acc[m][0], acc[m][1], acc[m][2], acc[m][3]};
        *(float4*)(op + (mg*9 + m)*4) = o4;
      }
    }
  }
}

// ---------------- distance helpers ----------------
__global__ __launch_bounds__(64) void zz_sq(const float* __restrict__ A, float* __restrict__ sq)
{
  int i = blockIdx.x, lane = threadIdx.x;
  const float* row = A + (size_t)i*(DI*DI);
  float s = 0.f;
  for (int k = lane; k < DI*DI; k += 64) { float v = row[k]; s = fmaf(v, v, s); }
  for (int off = 32; off; off >>= 1) s += __shfl_xor(s, off);
  if (!lane) sq[i] = s;
}

__global__ __launch_bounds__(256) void zz_dist(const float* __restrict__ A,
    const float* __restrict__ sq, float* __restrict__ dsum)
{
  __shared__ float Ai[64][65], Aj[64][65];
  __shared__ float red[256];
  int i0 = blockIdx.y*64, j0 = blockIdx.x*64;
  int tid = threadIdx.x, tx = tid % 16, ty = tid / 16;
  float acc[4][4] = {};
  for (int k0 = 0; k0 < DI*DI; k0 += 64) {
    for (int t = tid; t < 64*64; t += 256) {
      int r = t >> 6, kk = t & 63, gk = k0 + kk;
      float vi = 0.f, vj = 0.f;
      if (gk < DI*DI) {
        vi = A[(size_t)(i0 + r)*(DI*DI) + gk];
        vj = A[(size_t)(j0 + r)*(DI*DI) + gk];
      }
      Ai[r][kk] = vi; Aj[r][kk] = vj;
    }
    __syncthreads();
    #pragma unroll 8
    for (int kk = 0; kk < 64; ++kk) {
      float a[4], bb[4];
      #pragma unroll
      for (int u = 0; u < 4; ++u) a[u]  = Ai[ty*4 + u][kk];
      #pragma unroll
      for (int u = 0; u < 4; ++u) bb[u] = Aj[tx*4 + u][kk];
      #pragma unroll
      for (int u = 0; u < 4; ++u)
        #pragma unroll
        for (int v = 0; v < 4; ++v) acc[u][v] = fmaf(a[u], bb[v], acc[u][v]);
    }
    __syncthreads();
  }
  float s = 0.f;
  #pragma unroll
  for (int u = 0; u < 4; ++u)
    #pragma unroll
    for (int v = 0; v < 4; ++v) {
      float d2 = sq[i0 + ty*4 + u] + sq[j0 + tx*4 + v] - 2.f*acc[u][v];
      d2 = fmaxf(d2, 0.f);
      s += sqrtf(d2 + 1e-12f);
    }
  red[tid] = s; __syncthreads();
  for (int st = 128; st; st >>= 1) { if (tid < st) red[tid] += red[tid + st]; __syncthreads(); }
  if (!tid) atomicAdd(dsum, red[0]);
}

__global__ void zz_dist_fin(const float* dsum, float* out)
{
  out[0] = dsum[0] * (1.f/((float)NB*(float)NB));
}

// ---------------- token GEMM via MFMA: C(MxN) = [relu]( A(MxK,f32->bf16) @ BT(bf16 [N][K])^T + bias [+res] ) ----------------
// K multiple of 32; N multiple of 32. No LDS, no barriers. 4 waves = 64 rows per block.
template<int RELU, int RES>
__global__ __launch_bounds__(256) void zz_mgemm(const float* __restrict__ A,
    const short* __restrict__ BT, const float* __restrict__ bias,
    const float* __restrict__ res, float* __restrict__ C, int M, int N, int K)
{
  int wave = threadIdx.x >> 6, lane = threadIdx.x & 63;
  int m0 = blockIdx.x*64 + wave*16;
  if (m0 >= M) return;
  int r = lane & 15, g = lane >> 4;
  int arow = m0 + r; if (arow >= M) arow = M - 1;
  const float* Ap = A + (size_t)arow*K + g*8;
  int NP = N >> 5;
  for (int ntp = 0; ntp < NP; ++ntp) {
    int n0 = ntp*32;
    const short* B0 = BT + (size_t)(n0 + r)*K + g*8;
    const short* B1 = B0 + (size_t)16*K;
    f32x4 acc0 = {0.f,0.f,0.f,0.f}, acc1 = {0.f,0.f,0.f,0.f};
    #pragma unroll 5
    for (int k0 = 0; k0 < K; k0 += 32) {
      bf16x8 af = zz_cvt8(Ap + k0);
      bf16x8 b0 = *(const bf16x8*)(B0 + k0);
      bf16x8 b1 = *(const bf16x8*)(B1 + k0);
      acc0 = __builtin_amdgcn_mfma_f32_16x16x32_bf16(af, b0, acc0, 0, 0, 0);
      acc1 = __builtin_amdgcn_mfma_f32_16x16x32_bf16(af, b1, acc1, 0, 0, 0);
    }
    #pragma unroll
    for (int j = 0; j < 4; ++j) {
      int row = m0 + g*4 + j;
      if (row >= M) continue;
      int c0 = n0 + r, c1 = n0 + 16 + r;
      float v0 = acc0[j] + bias[c0];
      float v1 = acc1[j] + bias[c1];
      if (RES) { v0 += res[(size_t)row*N + c0]; v1 += res[(size_t)row*N + c1]; }
      if (RELU) { v0 = fmaxf(v0, 0.f); v1 = fmaxf(v1, 0.f); }
      C[(size_t)row*N + c0] = v0;
      C[(size_t)row*N + c1] = v1;
    }
  }
}

// ---------------- f32 tiled GEMM (small head GEMMs): 64x128 tile, 4x8 micro ----------------
template<int RELU, int RES>
__global__ __launch_bounds__(256) void zz_gemm(const float* __restrict__ A,
    const float* __restrict__ Bw, const float* __restrict__ bias,
    const float* __restrict__ res, float* __restrict__ C, int M, int N, int K)
{
  __shared__ float As[64][33];
  __shared__ float Bs[32][136];
  int m0 = blockIdx.y*64, n0 = blockIdx.x*128;
  int tid = threadIdx.x, tx = tid & 15, ty = tid >> 4;
  float acc[4][8] = {};
  for (int k0 = 0; k0 < K; k0 += 32) {
    for (int i = tid; i < 64*32; i += 256) {
      int rr = i >> 5, kk = i & 31;
      int gm = m0 + rr, gk = k0 + kk;
      As[rr][kk] = (gm < M && gk < K) ? A[(size_t)gm*K + gk] : 0.f;
    }
    for (int i = tid; i < 32*128; i += 256) {
      int kk = i >> 7, n = i & 127;
      int gk = k0 + kk, gn = n0 + n;
      Bs[kk][n] = (gk < K && gn < N) ? Bw[(size_t)gk*N + gn] : 0.f;
    }
    __syncthreads();
    #pragma unroll 4
    for (int kk = 0; kk < 32; ++kk) {
      float a[4];
      #pragma unroll
      for (int u = 0; u < 4; ++u) a[u] = As[ty*4 + u][kk];
      float4 b0 = *(const float4*)&Bs[kk][tx*8];
      float4 b1 = *(const float4*)&Bs[kk][tx*8 + 4];
      float b[8] = {b0.x,b0.y,b0.z,b0.w,b1.x,b1.y,b1.z,b1.w};
      #pragma unroll
      for (int u = 0; u < 4; ++u)
        #pragma unroll
        for (int v = 0; v < 8; ++v) acc[u][v] = fmaf(a[u], b[v], acc[u][v]);
    }
    __syncthreads();
  }
  #pragma unroll
  for (int u = 0; u < 4; ++u) {
    int gm = m0 + ty*4 + u;
    if (gm >= M) continue;
    #pragma unroll
    for (int v = 0; v < 8; ++v) {
      int gn = n0 + tx*8 + v;
      if (gn >= N) continue;
      float val = acc[u][v] + bias[gn];
      if (RES) val += res[(size_t)gm*N + gn];
      if (RELU) val = fmaxf(val, 0.f);
      C[(size_t)gm*N + gn] = val;
    }
  }
}

// ---------------- attention: block per (bl,h); one thread = one query; no inner barriers ----------------
__global__ __launch_bounds__(256) void zz_attn(const float* __restrict__ QKV,
    const int* __restrict__ lengths, float* __restrict__ O, int b0, int CB)
{
  __shared__ float Kl[S_LEN][DH+1];
  __shared__ float Vl[S_LEN][DH+1];
  int bl = blockIdx.x >> 2, h = blockIdx.x & 3;
  int tid = threadIdx.x;
  int len = lengths[b0 + bl];
  for (int i = tid; i < S_LEN*DH; i += 256) {
    int s = i / DH, d = i - s*DH;
    const float* base = QKV + ((size_t)s*CB + bl)*(3*DT) + h*DH + d;
    Kl[s][d] = base[DT];
    Vl[s][d] = base[2*DT];
  }
  __syncthreads();
  if (tid >= S_LEN) return;
  float q[DH];
  const float* qp = QKV + ((size_t)tid*CB + bl)*(3*DT) + h*DH;
  #pragma unroll
  for (int d = 0; d < DH; d += 4) {
    float4 t4 = *(const float4*)(qp + d);
    q[d] = t4.x; q[d+1] = t4.y; q[d+2] = t4.z; q[d+3] = t4.w;
  }
  float m = -3e38f, l = 0.f;
  float o[DH] = {};
  for (int t = 0; t < len; ++t) {
    float sc = 0.f;
    #pragma unroll
    for (int d = 0; d < DH; ++d) sc = fmaf(q[d], Kl[t][d], sc);
    sc *= 0.15811388300841897f;
    float mn = fmaxf(m, sc);
    float corr = exp2f((m - mn) * 1.44269504088896f);
    float p    = exp2f((sc - mn) * 1.44269504088896f);
    l = l*corr + p;
    #pragma unroll
    for (int d = 0; d < DH; ++d) o[d] = fmaf(p, Vl[t][d], o[d]*corr);
    m = mn;
  }
  float inv = 1.f / l;
  float* op = O + ((size_t)tid*CB + bl)*DT + h*DH;
  #pragma unroll
  for (int d = 0; d < DH; d += 4) {
    float4 o4 = {o[d]*inv, o[d+1]*inv, o[d+2]*inv, o[d+3]*inv};
    *(float4*)(op + d) = o4;
  }
}

// ---------------- layernorm over 160, one wave per token ----------------
__global__ __launch_bounds__(256) void zz_ln(const float* __restrict__ X,
    const float* __restrict__ g, const float* __restrict__ bt, float* __restrict__ Y, int ntok)
{
  int tok = blockIdx.x*4 + (threadIdx.x >> 6);
  if (tok >= ntok) return;
  int lane = threadIdx.x & 63;
  const float* x = X + (size_t)tok*DT;
  float v0 = x[lane], v1 = x[lane + 64];
  float v2 = (lane < 32) ? x[lane + 128] : 0.f;
  float s = v0 + v1 + v2;
  for (int off = 32; off; off >>= 1) s += __shfl_xor(s, off);
  float mean = s * (1.f/160.f);
  float d0 = v0 - mean, d1 = v1 - mean, d2 = (lane < 32) ? (v2 - mean) : 0.f;
  float q = d0*d0 + d1*d1 + d2*d2;
  for (int off = 32; off; off >>= 1) q += __shfl_xor(q, off);
  float inv = 1.f / sqrtf(q * (1.f/160.f) + 1e-5f);
  float* y = Y + (size_t)tok*DT;
  y[lane]      = d0*inv*g[lane]      + bt[lane];
  y[lane + 64] = d1*inv*g[lane + 64] + bt[lane + 64];
  if (lane < 32) y[lane + 128] = d2*inv*g[lane + 128] + bt[lane + 128];
}

// ---------------- masked mean + feat concat ----------------
__global__ __launch_bounds__(256) void zz_agg(const float* __restrict__ XCH,
    const int* __restrict__ lengths, const float* __restrict__ emb, float* __restrict__ feat,
    int b0, int CB)
{
  int bl = blockIdx.x, tid = threadIdx.x;
  int b = b0 + bl;
  int len = lengths[b];
  if (tid < DT) {
    float acc = 0.f;
    for (int s = 0; s < len; ++s) acc += XCH[((size_t)s*CB + bl)*DT + tid];
    feat[(size_t)b*DFIN + tid] = acc / (float)(len + 1);
  } else if (tid < DFIN) {
    feat[(size_t)b*DFIN + tid] = emb[b*DI + (tid - DT)];
  }
}

// ======================================================================
extern "C" void kernel_launch(void* const* d_in, const int* in_sizes, int n_in,
                              void* d_out, int out_size, void* d_ws, size_t ws_size,
                              hipStream_t stream)
{
  (void)in_sizes; (void)n_in; (void)out_size;
  const float* src     = (const float*)d_in[0];
  const float* statc   = (const float*)d_in[1];
  const float* times   = (const float*)d_in[2];
  const int*   lengths = (const int*)  d_in[3];
  const float* R_u     = (const float*)d_in[4];
  const float* emb_w   = (const float*)d_in[5];
  const float* emb_b   = (const float*)d_in[6];
  const float* W1      = (const float*)d_in[7];
  const float* a1_s    = (const float*)d_in[8];
  const float* a1_d    = (const float*)d_in[9];
  const float* W2      = (const float*)d_in[10];
  const float* a2_s    = (const float*)d_in[11];
  const float* a2_d    = (const float*)d_in[12];
  const float* attn_in_w  = (const float*)d_in[13];
  const float* attn_in_b  = (const float*)d_in[14];
  const float* attn_out_w = (const float*)d_in[15];
  const float* attn_out_b = (const float*)d_in[16];
  const float* ff1_w = (const float*)d_in[17];
  const float* ff1_b = (const float*)d_in[18];
  const float* ff2_w = (const float*)d_in[19];
  const float* ff2_b = (const float*)d_in[20];
  const float* ln1_g = (const float*)d_in[21];
  const float* ln1_b = (const float*)d_in[22];
  const float* ln2_g = (const float*)d_in[23];
  const float* ln2_b = (const float*)d_in[24];
  const float* mlp1_w = (const float*)d_in[25];
  const float* mlp1_b = (const float*)d_in[26];
  const float* mlp2_w = (const float*)d_in[27];
  const float* mlp2_b = (const float*)d_in[28];

  // ---- small persistent buffers (floats) ----
  float* ws = (float*)d_ws;
  float* A1    = ws;                 // 663,552
  float* A2    = ws + 663552;        // 663,552
  float* SS    = ws + 1327104;       // 18,432
  float* SD    = ws + 1345536;       // 18,432
  float* SQB   = ws + 1363968;       // 512
  float* DSUM  = ws + 1364480;       // 64
  float* EMB   = ws + 1364544;       // 18,432
  float* FEAT  = ws + 1382976;       // 100,352
  float* FFEAT = ws + 1483328;       // 100,352
  // bf16 weight area (shorts), 16B-aligned
  short* wb = (short*)(ws + 1583680);
  short* W1T   = wb;                 // 864*864 = 746,496
  short* W2T   = wb + 746496;        // 746,496
  short* WTqkv = wb + 1492992;       // 2*480*160 = 153,600
  short* WTao  = wb + 1646592;       // 2*160*160 = 51,200
  short* WTf1  = wb + 1697792;       // 2*128*160 = 40,960
  short* WTf2  = wb + 1738752;       // 2*160*128 = 40,960
  const size_t CHBASE = 1583680 + 889856;   // = 2,473,536 floats
  float* CH = ws + CHBASE;

  // ---- pick largest chunk size that fits ws_size ----
  // chunk floats = XCH 34400*CB + max(GAT 3*31104=93312*CB, TRANSF 199520*CB) = 233920*CB
  int CB = 8;
  const int cands[7] = {512, 256, 128, 64, 32, 16, 8};
  for (int c = 0; c < 7; ++c) {
    size_t need = 4ull * (CHBASE + 233920ull * (size_t)cands[c]);
    if (need <= ws_size) { CB = cands[c]; break; }
  }
  const int NCH = NB / CB;
  const int NTOKC = S_LEN * CB;

  float* XCH = CH;                         // 34,400*CB
  float* R0  = CH + (size_t)34400*CB;
  // GAT view (stride-864 buffers)
  float* Xc  = R0;                         // 31,104*CB
  float* XPc = R0 + (size_t)31104*CB;      // 31,104*CB
  float* H1c = R0 + (size_t)62208*CB;      // 31,104*CB
  // transformer view (GAT bufs dead)
  float* QKVc = R0;                        // 103,200*CB
  float* OAc  = R0 + (size_t)103200*CB;    // 34,400*CB
  float* Tc   = R0 + (size_t)137600*CB;    // 34,400*CB
  float* Yc   = R0 + (size_t)172000*CB;    // 27,520*CB

  hipMemsetAsync(DSUM, 0, 4, stream);
  zz_emb<<<dim3(CDIV(NB*DI,256)), 256, 0, stream>>>(statc, emb_w, emb_b, EMB);

  // ---- one-time weight transpose+bf16 conversions ----
  zz_wcvt<<<dim3(CDIV(FINP*FINP,256)), 256, 0, stream>>>(W1, W1T, FIN, FIN, FINP, FINP);
  zz_wcvt<<<dim3(CDIV(FINP*FINP,256)), 256, 0, stream>>>(W2, W2T, FIN, FIN, FINP, FINP);
  for (int l = 0; l < 2; ++l) {
    zz_wcvt<<<dim3(CDIV(480*160,256)), 256, 0, stream>>>(attn_in_w + (size_t)l*DT*3*DT,
        WTqkv + (size_t)l*76800, DT, 3*DT, DT, 3*DT);
    zz_wcvt<<<dim3(CDIV(160*160,256)), 256, 0, stream>>>(attn_out_w + (size_t)l*DT*DT,
        WTao + (size_t)l*25600, DT, DT, DT, DT);
    zz_wcvt<<<dim3(CDIV(128*160,256)), 256, 0, stream>>>(ff1_w + (size_t)l*DT*NHID,
        WTf1 + (size_t)l*20480, DT, NHID, DT, NHID);
    zz_wcvt<<<dim3(CDIV(160*128,256)), 256, 0, stream>>>(ff2_w + (size_t)l*NHID*DT,
        WTf2 + (size_t)l*20480, NHID, DT, NHID, DT);
  }

  for (int ch = 0; ch < NCH; ++ch) {
    int b0 = ch * CB;
    // ---- GAT stack (chunk) ----
    zz_build_x<<<dim3(CDIV(CB*DI*S_LEN,256)), 256, 0, stream>>>(src, R_u, Xc, b0, CB);
    zz_zeropad<<<dim3(CDIV(CB*DI,256)), 256, 0, stream>>>(Xc, CB);
    zz_gat_mfma<<<dim3(2, CB), 256, 0, stream>>>(Xc, W1T, XPc, CB);
    zz_gat_attvec<<<dim3(DI, CB), 64, 0, stream>>>(XPc, a1_s, a1_d, SS, SD, b0);
    zz_gat_alpha<<<dim3(CB), 256, 0, stream>>>(SS, SD, (const float*)nullptr, A1, b0);
    zz_gat_apply<<<dim3(4, CB), 256, 0, stream>>>(A1, XPc, H1c, 0, b0, CB);
    zz_zeropad<<<dim3(CDIV(CB*DI,256)), 256, 0, stream>>>(H1c, CB);
    zz_gat_mfma<<<dim3(2, CB), 256, 0, stream>>>(H1c, W2T, XPc, CB);
    zz_gat_attvec<<<dim3(DI, CB), 64, 0, stream>>>(XPc, a2_s, a2_d, SS, SD, b0);
    zz_gat_alpha<<<dim3(CB), 256, 0, stream>>>(SS, SD, A1, A2, b0);
    zz_gat_apply<<<dim3(4, CB), 256, 0, stream>>>(A2, XPc, XCH, 1, b0, CB);
    zz_pe<<<dim3(CDIV(CB*S_LEN*16,256)), 256, 0, stream>>>(times, XCH, b0, CB);

    // ---- transformer (chunk) ----
    for (int l = 0; l < 2; ++l) {
      zz_mgemm<0,0><<<dim3(CDIV(NTOKC,64)), 256, 0, stream>>>(XCH,
          WTqkv + (size_t)l*76800, attn_in_b + l*3*DT, nullptr, QKVc, NTOKC, 3*DT, DT);
      zz_attn<<<dim3(CB*NH), 256, 0, stream>>>(QKVc, lengths, OAc, b0, CB);
      zz_mgemm<0,1><<<dim3(CDIV(NTOKC,64)), 256, 0, stream>>>(OAc,
          WTao + (size_t)l*25600, attn_out_b + l*DT, XCH, Tc, NTOKC, DT, DT);
      zz_ln<<<dim3(CDIV(NTOKC,4)), 256, 0, stream>>>(Tc, ln1_g + l*DT, ln1_b + l*DT, XCH, NTOKC);
      zz_mgemm<1,0><<<dim3(CDIV(NTOKC,64)), 256, 0, stream>>>(XCH,
          WTf1 + (size_t)l*20480, ff1_b + l*NHID, nullptr, Yc, NTOKC, NHID, DT);
      zz_mgemm<0,1><<<dim3(CDIV(NTOKC,64)), 256, 0, stream>>>(Yc,
          WTf2 + (size_t)l*20480, ff2_b + l*DT, XCH, Tc, NTOKC, DT, NHID);
      zz_ln<<<dim3(CDIV(NTOKC,4)), 256, 0, stream>>>(Tc, ln2_g + l*DT, ln2_b + l*DT, XCH, NTOKC);
    }

    zz_agg<<<dim3(CB), 256, 0, stream>>>(XCH, lengths, EMB, FEAT, b0, CB);
  }

  // ---- distance from alpha2 (full batch) ----
  zz_sq<<<dim3(NB), 64, 0, stream>>>(A2, SQB);
  zz_dist<<<dim3(8, 8), 256, 0, stream>>>(A2, SQB, DSUM);
  zz_dist_fin<<<1, 1, 0, stream>>>(DSUM, (float*)d_out + 1024);

  // ---- head (f32, tiny) ----
  zz_gemm<1,0><<<dim3(CDIV(DFIN,128), CDIV(NB,64)), 256, 0, stream>>>(FEAT, mlp1_w, mlp1_b,
      nullptr, FFEAT, NB, DFIN, DFIN);
  zz_gemm<0,0><<<dim3(1, CDIV(NB,64)), 256, 0, stream>>>(FFEAT, mlp2_w, mlp2_b,
      nullptr, (float*)d_out, NB, 2, DFIN);
}

// Round 6
// 3595.823 us; speedup vs baseline: 3.1859x; 1.0012x over previous
//
#include <hip/hip_runtime.h>
#include <hip/hip_bf16.h>
#include <math.h>

#define S_LEN 215
#define NB    512
#define DI    36
#define DMODEL 144
#define DT    160
#define NH    4
#define DH    40
#define NHID  128
#define FIN   860
#define FINP  864          // K-padded
#define DFIN  196
#define SP    216          // S_LEN padded for LDS rows (div by 8, 16B-aligned)
#define CDIV(a,b) (((a)+(b)-1)/(b))

typedef __attribute__((ext_vector_type(8))) short bf16x8;
typedef __attribute__((ext_vector_type(4))) float f32x4;

__device__ inline bf16x8 zz_cvt8(const float* __restrict__ p) {
  float4 lo = *(const float4*)p;
  float4 hi = *(const float4*)(p + 4);
  union { bf16x8 v; __hip_bfloat16 h[8]; } u;
  u.h[0] = __float2bfloat16(lo.x); u.h[1] = __float2bfloat16(lo.y);
  u.h[2] = __float2bfloat16(lo.z); u.h[3] = __float2bfloat16(lo.w);
  u.h[4] = __float2bfloat16(hi.x); u.h[5] = __float2bfloat16(hi.y);
  u.h[6] = __float2bfloat16(hi.z); u.h[7] = __float2bfloat16(hi.w);
  return u.v;
}

// ---------------- weight transpose + bf16 convert: WT[n][k] = bf16(W[k][n]) ----------------
__global__ __launch_bounds__(256) void zz_wcvt(const float* __restrict__ W,
    short* __restrict__ WT, int K, int N, int Kpad, int Npad)
{
  int idx = blockIdx.x*256 + threadIdx.x;
  if (idx >= Npad*Kpad) return;
  int n = idx / Kpad, k = idx % Kpad;
  float v = (n < N && k < K) ? W[(size_t)k*N + n] : 0.f;
  union { __hip_bfloat16 h; short s; } c;
  c.h = __float2bfloat16(v);
  WT[idx] = c.s;
}

// ---------------- build x chunk ----------------
__global__ __launch_bounds__(256) void zz_build_x(const float* __restrict__ src,
    const float* __restrict__ R_u, float* __restrict__ X, int b0, int CB)
{
  int idx = blockIdx.x*256 + threadIdx.x;           // (bl,i,s)
  if (idx >= CB*DI*S_LEN) return;
  int s = idx % S_LEN; int t = idx / S_LEN; int i = t % DI; int bl = t / DI;
  float v = src[((size_t)s*NB + b0 + bl)*(2*DI) + i];
  float4 r = *(const float4*)(R_u + i*4);
  float4 o;
  o.x = fmaxf(v*r.x, 0.f); o.y = fmaxf(v*r.y, 0.f);
  o.z = fmaxf(v*r.z, 0.f); o.w = fmaxf(v*r.w, 0.f);
  *(float4*)(X + (size_t)(bl*DI + i)*FINP + s*4) = o;
}

// ---------------- zero pad cols 860..863 ----------------
__global__ __launch_bounds__(256) void zz_zeropad(float* __restrict__ buf, int CB)
{
  int idx = blockIdx.x*256 + threadIdx.x;
  if (idx >= CB*DI) return;
  float4 z = {0.f,0.f,0.f,0.f};
  *(float4*)(buf + (size_t)idx*FINP + FIN) = z;
}

// ---------------- positional encoding ----------------
__global__ __launch_bounds__(256) void zz_pe(const float* __restrict__ times,
    float* __restrict__ XCH, int b0, int CB)
{
  int idx = blockIdx.x*256 + threadIdx.x;           // (tl, k)
  if (idx >= CB*S_LEN*16) return;
  int k = idx & 15; int tl = idx >> 4;
  int bl = tl % CB; int s = tl / CB;
  int j = k & 7;
  float ts = powf(215.f, (float)j * (1.f/7.f)) * 100.f;
  float sc = times[(size_t)s*NB + b0 + bl] / ts;
  XCH[(size_t)tl*DT + DMODEL + k] = (k < 8) ? sinf(sc) : cosf(sc);
}

// ---------------- emb ----------------
__global__ __launch_bounds__(256) void zz_emb(const float* __restrict__ st,
    const float* __restrict__ w, const float* __restrict__ bias, float* __restrict__ emb)
{
  int idx = blockIdx.x*256 + threadIdx.x;
  if (idx >= NB*DI) return;
  int b = idx / DI, k = idx % DI;
  float acc = bias[k];
  #pragma unroll
  for (int j = 0; j < 9; ++j) acc = fmaf(st[b*9 + j], w[j*DI + k], acc);
  emb[idx] = acc;
}

// ---------------- GAT GEMM via MFMA ----------------
__global__ __launch_bounds__(256) void zz_gat_mfma(const float* __restrict__ X,
    const short* __restrict__ WT, float* __restrict__ XP, int CB)
{
  int bl = blockIdx.y, half = blockIdx.x;
  int wave = threadIdx.x >> 6, lane = threadIdx.x & 63;
  int r = lane & 15, g = lane >> 4;
  const float* Xb = X + (size_t)bl*DI*FINP;
  float* XPb = XP + (size_t)bl*DI*FINP;
  int p0 = half ? 14 : 0, p1 = half ? 27 : 14;
  int ntasks = 3 * (p1 - p0);
  for (int task = wave; task < ntasks; task += 4) {
    int mt = task % 3; int ntp = p0 + task / 3;
    int m0 = mt*16;
    int arow = m0 + r; if (arow > DI-1) arow = DI-1;
    const float* Ap = Xb + (size_t)arow*FINP + g*8;
    int n0 = ntp*32;
    const short* B0 = WT + (size_t)(n0 + r)*FINP + g*8;
    const short* B1 = B0 + (size_t)16*FINP;
    f32x4 acc0 = {0.f,0.f,0.f,0.f}, acc1 = {0.f,0.f,0.f,0.f};
    #pragma unroll 3
    for (int k0 = 0; k0 < FINP; k0 += 32) {
      bf16x8 af = zz_cvt8(Ap + k0);
      bf16x8 b0 = *(const bf16x8*)(B0 + k0);
      bf16x8 b1 = *(const bf16x8*)(B1 + k0);
      acc0 = __builtin_amdgcn_mfma_f32_16x16x32_bf16(af, b0, acc0, 0, 0, 0);
      acc1 = __builtin_amdgcn_mfma_f32_16x16x32_bf16(af, b1, acc1, 0, 0, 0);
    }
    #pragma unroll
    for (int j = 0; j < 4; ++j) {
      int row = m0 + g*4 + j;
      if (row < DI) {
        int c0 = n0 + r, c1 = n0 + 16 + r;
        if (c0 < FIN) XPb[(size_t)row*FINP + c0] = acc0[j];
        if (c1 < FIN) XPb[(size_t)row*FINP + c1] = acc1[j];
      }
    }
  }
}

// ---------------- per-row dots ----------------
__global__ __launch_bounds__(64) void zz_gat_attvec(const float* __restrict__ XP,
    const float* __restrict__ a_s, const float* __restrict__ a_d,
    float* __restrict__ ss, float* __restrict__ sd, int b0)
{
  int i = blockIdx.x, bl = blockIdx.y, lane = threadIdx.x;
  const float* row = XP + ((size_t)bl*DI + i)*FINP;
  float ps = 0.f, pd = 0.f;
  for (int k = lane; k < FIN; k += 64) {
    float v = row[k];
    ps = fmaf(v, a_s[k], ps);
    pd = fmaf(v, a_d[k], pd);
  }
  for (int off = 32; off; off >>= 1) { ps += __shfl_xor(ps, off); pd += __shfl_xor(pd, off); }
  if (!lane) { ss[(b0 + bl)*DI + i] = ps; sd[(b0 + bl)*DI + i] = pd; }
}

// ---------------- alpha softmax ----------------
__global__ __launch_bounds__(256) void zz_gat_alpha(const float* __restrict__ ss,
    const float* __restrict__ sd, const float* __restrict__ edge, float* __restrict__ alpha, int b0)
{
  int b = b0 + blockIdx.x;
  int wv = threadIdx.x >> 6, lane = threadIdx.x & 63;
  for (int i = wv; i < DI; i += 4) {
    float di = sd[b*DI + i];
    float e = -3e38f, x = 0.f;
    if (lane < DI) {
      x = di + ss[b*DI + lane];
      x = (x >= 0.f) ? x : 0.2f*x;
      e = x;
    }
    float m = e;
    for (int off = 32; off; off >>= 1) m = fmaxf(m, __shfl_xor(m, off));
    float p = (lane < DI) ? expf(e - m) : 0.f;
    float s = p;
    for (int off = 32; off; off >>= 1) s += __shfl_xor(s, off);
    if (lane < DI) {
      float a = p / s;
      size_t o = ((size_t)b*DI + i)*DI + lane;
      if (edge) a *= edge[o];
      alpha[o] = a;
    }
  }
}

// ---------------- gat apply ----------------
__global__ __launch_bounds__(256) void zz_gat_apply(const float* __restrict__ alpha,
    const float* __restrict__ XP, float* __restrict__ out, int mode, int b0, int CB)
{
  __shared__ float Al[DI][37];
  __shared__ float Xs[DI][260];
  int bl = blockIdx.y, n0 = blockIdx.x * 256;
  int tid = threadIdx.x;
  int nt = tid & 63, mg = tid >> 6;
  const float* ab = alpha + ((size_t)(b0 + bl))*DI*DI;
  for (int i = tid; i < DI*DI; i += 256) Al[i/DI][i%DI] = ab[i];
  const float* XPb = XP + (size_t)bl*DI*FINP;
  for (int i = tid; i < DI*256; i += 256) {
    int k = i >> 8, nn = i & 255, gn = n0 + nn;
    Xs[k][nn] = (gn < FIN) ? XPb[(size_t)k*FINP + gn] : 0.f;
  }
  __syncthreads();
  float acc[9][4] = {};
  #pragma unroll 4
  for (int k = 0; k < DI; ++k) {
    float4 x4 = *(const float4*)&Xs[k][nt*4];
    float xb[4] = {x4.x, x4.y, x4.z, x4.w};
    #pragma unroll
    for (int m = 0; m < 9; ++m) {
      float av = Al[mg*9 + m][k];
      #pragma unroll
      for (int v = 0; v < 4; ++v) acc[m][v] = fmaf(av, xb[v], acc[m][v]);
    }
  }
  int gn = n0 + nt*4;
  if (gn < FIN) {
    if (mode == 0) {
      float* ob = out + (size_t)bl*DI*FINP;
      #pragma unroll
      for (int m = 0; m < 9; ++m) {
        float4 o4 = {acc[m][0], acc[m][1], acc[m][2], acc[m][3]};
        *(float4*)(ob + (size_t)(mg*9 + m)*FINP + gn) = o4;
      }
    } else {
      int s = gn >> 2;
      float* op = out + ((size_t)s*CB + bl)*DT;
      #pragma unroll
      for (int m = 0; m < 9; ++m) {
        float4 o4 = {acc[m][0], acc[m][1], acc[m][2], acc[m][3]};
        *(float4*)(op + (mg*9 + m)*4) = o4;
      }
    }
  }
}

// ---------------- distance helpers ----------------
__global__ __launch_bounds__(64) void zz_sq(const float* __restrict__ A, float* __restrict__ sq)
{
  int i = blockIdx.x, lane = threadIdx.x;
  const float* row = A + (size_t)i*(DI*DI);
  float s = 0.f;
  for (int k = lane; k < DI*DI; k += 64) { float v = row[k]; s = fmaf(v, v, s); }
  for (int off = 32; off; off >>= 1) s += __shfl_xor(s, off);
  if (!lane) sq[i] = s;
}

__global__ __launch_bounds__(256) void zz_dist(const float* __restrict__ A,
    const float* __restrict__ sq, float* __restrict__ dsum)
{
  __shared__ float Ai[64][65], Aj[64][65];
  __shared__ float red[256];
  int i0 = blockIdx.y*64, j0 = blockIdx.x*64;
  int tid = threadIdx.x, tx = tid % 16, ty = tid / 16;
  float acc[4][4] = {};
  for (int k0 = 0; k0 < DI*DI; k0 += 64) {
    for (int t = tid; t < 64*64; t += 256) {
      int r = t >> 6, kk = t & 63, gk = k0 + kk;
      float vi = 0.f, vj = 0.f;
      if (gk < DI*DI) {
        vi = A[(size_t)(i0 + r)*(DI*DI) + gk];
        vj = A[(size_t)(j0 + r)*(DI*DI) + gk];
      }
      Ai[r][kk] = vi; Aj[r][kk] = vj;
    }
    __syncthreads();
    #pragma unroll 8
    for (int kk = 0; kk < 64; ++kk) {
      float a[4], bb[4];
      #pragma unroll
      for (int u = 0; u < 4; ++u) a[u]  = Ai[ty*4 + u][kk];
      #pragma unroll
      for (int u = 0; u < 4; ++u) bb[u] = Aj[tx*4 + u][kk];
      #pragma unroll
      for (int u = 0; u < 4; ++u)
        #pragma unroll
        for (int v = 0; v < 4; ++v) acc[u][v] = fmaf(a[u], bb[v], acc[u][v]);
    }
    __syncthreads();
  }
  float s = 0.f;
  #pragma unroll
  for (int u = 0; u < 4; ++u)
    #pragma unroll
    for (int v = 0; v < 4; ++v) {
      float d2 = sq[i0 + ty*4 + u] + sq[j0 + tx*4 + v] - 2.f*acc[u][v];
      d2 = fmaxf(d2, 0.f);
      s += sqrtf(d2 + 1e-12f);
    }
  red[tid] = s; __syncthreads();
  for (int st = 128; st; st >>= 1) { if (tid < st) red[tid] += red[tid + st]; __syncthreads(); }
  if (!tid) atomicAdd(dsum, red[0]);
}

__global__ void zz_dist_fin(const float* dsum, float* out)
{
  out[0] = dsum[0] * (1.f/((float)NB*(float)NB));
}

// ---------------- token GEMM via MFMA ----------------
template<int RELU, int RES>
__global__ __launch_bounds__(256) void zz_mgemm(const float* __restrict__ A,
    const short* __restrict__ BT, const float* __restrict__ bias,
    const float* __restrict__ res, float* __restrict__ C, int M, int N, int K)
{
  int wave = threadIdx.x >> 6, lane = threadIdx.x & 63;
  int m0 = blockIdx.x*64 + wave*16;
  if (m0 >= M) return;
  int r = lane & 15, g = lane >> 4;
  int arow = m0 + r; if (arow >= M) arow = M - 1;
  const float* Ap = A + (size_t)arow*K + g*8;
  int NP = N >> 5;
  for (int ntp = 0; ntp < NP; ++ntp) {
    int n0 = ntp*32;
    const short* B0 = BT + (size_t)(n0 + r)*K + g*8;
    const short* B1 = B0 + (size_t)16*K;
    f32x4 acc0 = {0.f,0.f,0.f,0.f}, acc1 = {0.f,0.f,0.f,0.f};
    #pragma unroll 5
    for (int k0 = 0; k0 < K; k0 += 32) {
      bf16x8 af = zz_cvt8(Ap + k0);
      bf16x8 b0 = *(const bf16x8*)(B0 + k0);
      bf16x8 b1 = *(const bf16x8*)(B1 + k0);
      acc0 = __builtin_amdgcn_mfma_f32_16x16x32_bf16(af, b0, acc0, 0, 0, 0);
      acc1 = __builtin_amdgcn_mfma_f32_16x16x32_bf16(af, b1, acc1, 0, 0, 0);
    }
    #pragma unroll
    for (int j = 0; j < 4; ++j) {
      int row = m0 + g*4 + j;
      if (row >= M) continue;
      int c0 = n0 + r, c1 = n0 + 16 + r;
      float v0 = acc0[j] + bias[c0];
      float v1 = acc1[j] + bias[c1];
      if (RES) { v0 += res[(size_t)row*N + c0]; v1 += res[(size_t)row*N + c1]; }
      if (RELU) { v0 = fmaxf(v0, 0.f); v1 = fmaxf(v1, 0.f); }
      C[(size_t)row*N + c0] = v0;
      C[(size_t)row*N + c1] = v1;
    }
  }
}

// ---------------- f32 tiled GEMM (head) ----------------
template<int RELU, int RES>
__global__ __launch_bounds__(256) void zz_gemm(const float* __restrict__ A,
    const float* __restrict__ Bw, const float* __restrict__ bias,
    const float* __restrict__ res, float* __restrict__ C, int M, int N, int K)
{
  __shared__ float As[64][33];
  __shared__ float Bs[32][136];
  int m0 = blockIdx.y*64, n0 = blockIdx.x*128;
  int tid = threadIdx.x, tx = tid & 15, ty = tid >> 4;
  float acc[4][8] = {};
  for (int k0 = 0; k0 < K; k0 += 32) {
    for (int i = tid; i < 64*32; i += 256) {
      int rr = i >> 5, kk = i & 31;
      int gm = m0 + rr, gk = k0 + kk;
      As[rr][kk] = (gm < M && gk < K) ? A[(size_t)gm*K + gk] : 0.f;
    }
    for (int i = tid; i < 32*128; i += 256) {
      int kk = i >> 7, n = i & 127;
      int gk = k0 + kk, gn = n0 + n;
      Bs[kk][n] = (gk < K && gn < N) ? Bw[(size_t)gk*N + gn] : 0.f;
    }
    __syncthreads();
    #pragma unroll 4
    for (int kk = 0; kk < 32; ++kk) {
      float a[4];
      #pragma unroll
      for (int u = 0; u < 4; ++u) a[u] = As[ty*4 + u][kk];
      float4 b0 = *(const float4*)&Bs[kk][tx*8];
      float4 b1 = *(const float4*)&Bs[kk][tx*8 + 4];
      float b[8] = {b0.x,b0.y,b0.z,b0.w,b1.x,b1.y,b1.z,b1.w};
      #pragma unroll
      for (int u = 0; u < 4; ++u)
        #pragma unroll
        for (int v = 0; v < 8; ++v) acc[u][v] = fmaf(a[u], b[v], acc[u][v]);
    }
    __syncthreads();
  }
  #pragma unroll
  for (int u = 0; u < 4; ++u) {
    int gm = m0 + ty*4 + u;
    if (gm >= M) continue;
    #pragma unroll
    for (int v = 0; v < 8; ++v) {
      int gn = n0 + tx*8 + v;
      if (gn >= N) continue;
      float val = acc[u][v] + bias[gn];
      if (RES) val += res[(size_t)gm*N + gn];
      if (RELU) val = fmaxf(val, 0.f);
      C[(size_t)gm*N + gn] = val;
    }
  }
}

// ---------------- attention: transposed K/V LDS, 8-key tiles, one rescale per tile ----------------
__global__ __launch_bounds__(256) void zz_attn(const float* __restrict__ QKV,
    const int* __restrict__ lengths, float* __restrict__ O, int b0, int CB)
{
  __shared__ float Kt[DH][SP];   // [d][t], broadcast float4 reads
  __shared__ float Vt[DH][SP];
  int bl = blockIdx.x >> 2, h = blockIdx.x & 3;
  int tid = threadIdx.x;
  int len = lengths[b0 + bl];
  for (int i = tid; i < S_LEN*DH; i += 256) {
    int s = i / DH, d = i - s*DH;
    const float* base = QKV + ((size_t)s*CB + bl)*(3*DT) + h*DH + d;
    Kt[d][s] = base[DT];
    Vt[d][s] = base[2*DT];
  }
  __syncthreads();
  if (tid >= S_LEN) return;

  const float LOG2E = 1.44269504088896f;
  float q[DH];
  const float* qp = QKV + ((size_t)tid*CB + bl)*(3*DT) + h*DH;
  #pragma unroll
  for (int d = 0; d < DH; d += 4) {
    float4 t4 = *(const float4*)(qp + d);
    q[d]   = t4.x * 0.15811388300841897f;
    q[d+1] = t4.y * 0.15811388300841897f;
    q[d+2] = t4.z * 0.15811388300841897f;
    q[d+3] = t4.w * 0.15811388300841897f;
  }
  float m = -3e38f, l = 0.f;
  float o[DH] = {};
  int nt8 = len & ~7;
  for (int t0 = 0; t0 < nt8; t0 += 8) {
    float s8[8] = {};
    #pragma unroll
    for (int d = 0; d < DH; ++d) {
      float4 a = *(const float4*)&Kt[d][t0];
      float4 b = *(const float4*)&Kt[d][t0 + 4];
      float qd = q[d];
      s8[0] = fmaf(qd, a.x, s8[0]); s8[1] = fmaf(qd, a.y, s8[1]);
      s8[2] = fmaf(qd, a.z, s8[2]); s8[3] = fmaf(qd, a.w, s8[3]);
      s8[4] = fmaf(qd, b.x, s8[4]); s8[5] = fmaf(qd, b.y, s8[5]);
      s8[6] = fmaf(qd, b.z, s8[6]); s8[7] = fmaf(qd, b.w, s8[7]);
    }
    float tmax = fmaxf(fmaxf(fmaxf(s8[0], s8[1]), fmaxf(s8[2], s8[3])),
                       fmaxf(fmaxf(s8[4], s8[5]), fmaxf(s8[6], s8[7])));
    float mn = fmaxf(m, tmax);
    float corr = exp2f((m - mn) * LOG2E);
    m = mn;
    l *= corr;
    #pragma unroll
    for (int d = 0; d < DH; ++d) o[d] *= corr;
    float p8[8];
    #pragma unroll
    for (int i = 0; i < 8; ++i) { p8[i] = exp2f((s8[i] - m) * LOG2E); l += p8[i]; }
    #pragma unroll
    for (int d = 0; d < DH; ++d) {
      float4 a = *(const float4*)&Vt[d][t0];
      float4 b = *(const float4*)&Vt[d][t0 + 4];
      float od = o[d];
      od = fmaf(p8[0], a.x, od); od = fmaf(p8[1], a.y, od);
      od = fmaf(p8[2], a.z, od); od = fmaf(p8[3], a.w, od);
      od = fmaf(p8[4], b.x, od); od = fmaf(p8[5], b.y, od);
      od = fmaf(p8[6], b.z, od); od = fmaf(p8[7], b.w, od);
      o[d] = od;
    }
  }
  for (int t = nt8; t < len; ++t) {
    float sc = 0.f;
    #pragma unroll
    for (int d = 0; d < DH; ++d) sc = fmaf(q[d], Kt[d][t], sc);
    float mn = fmaxf(m, sc);
    float corr = exp2f((m - mn) * LOG2E);
    float p    = exp2f((sc - mn) * LOG2E);
    l = l*corr + p;
    #pragma unroll
    for (int d = 0; d < DH; ++d) o[d] = fmaf(p, Vt[d][t], o[d]*corr);
    m = mn;
  }
  float inv = 1.f / l;
  float* op = O + ((size_t)tid*CB + bl)*DT + h*DH;
  #pragma unroll
  for (int d = 0; d < DH; d += 4) {
    float4 o4 = {o[d]*inv, o[d+1]*inv, o[d+2]*inv, o[d+3]*inv};
    *(float4*)(op + d) = o4;
  }
}

// ---------------- layernorm ----------------
__global__ __launch_bounds__(256) void zz_ln(const float* __restrict__ X,
    const float* __restrict__ g, const float* __restrict__ bt, float* __restrict__ Y, int ntok)
{
  int tok = blockIdx.x*4 + (threadIdx.x >> 6);
  if (tok >= ntok) return;
  int lane = threadIdx.x & 63;
  const float* x = X + (size_t)tok*DT;
  float v0 = x[lane], v1 = x[lane + 64];
  float v2 = (lane < 32) ? x[lane + 128] : 0.f;
  float s = v0 + v1 + v2;
  for (int off = 32; off; off >>= 1) s += __shfl_xor(s, off);
  float mean = s * (1.f/160.f);
  float d0 = v0 - mean, d1 = v1 - mean, d2 = (lane < 32) ? (v2 - mean) : 0.f;
  float q = d0*d0 + d1*d1 + d2*d2;
  for (int off = 32; off; off >>= 1) q += __shfl_xor(q, off);
  float inv = 1.f / sqrtf(q * (1.f/160.f) + 1e-5f);
  float* y = Y + (size_t)tok*DT;
  y[lane]      = d0*inv*g[lane]      + bt[lane];
  y[lane + 64] = d1*inv*g[lane + 64] + bt[lane + 64];
  if (lane < 32) y[lane + 128] = d2*inv*g[lane + 128] + bt[lane + 128];
}

// ---------------- masked mean + feat concat ----------------
__global__ __launch_bounds__(256) void zz_agg(const float* __restrict__ XCH,
    const int* __restrict__ lengths, const float* __restrict__ emb, float* __restrict__ feat,
    int b0, int CB)
{
  int bl = blockIdx.x, tid = threadIdx.x;
  int b = b0 + bl;
  int len = lengths[b];
  if (tid < DT) {
    float acc = 0.f;
    for (int s = 0; s < len; ++s) acc += XCH[((size_t)s*CB + bl)*DT + tid];
    feat[(size_t)b*DFIN + tid] = acc / (float)(len + 1);
  } else if (tid < DFIN) {
    feat[(size_t)b*DFIN + tid] = emb[b*DI + (tid - DT)];
  }
}

// ======================================================================
extern "C" void kernel_launch(void* const* d_in, const int* in_sizes, int n_in,
                              void* d_out, int out_size, void* d_ws, size_t ws_size,
                              hipStream_t stream)
{
  (void)in_sizes; (void)n_in; (void)out_size;
  const float* src     = (const float*)d_in[0];
  const float* statc   = (const float*)d_in[1];
  const float* times   = (const float*)d_in[2];
  const int*   lengths = (const int*)  d_in[3];
  const float* R_u     = (const float*)d_in[4];
  const float* emb_w   = (const float*)d_in[5];
  const float* emb_b   = (const float*)d_in[6];
  const float* W1      = (const float*)d_in[7];
  const float* a1_s    = (const float*)d_in[8];
  const float* a1_d    = (const float*)d_in[9];
  const float* W2      = (const float*)d_in[10];
  const float* a2_s    = (const float*)d_in[11];
  const float* a2_d    = (const float*)d_in[12];
  const float* attn_in_w  = (const float*)d_in[13];
  const float* attn_in_b  = (const float*)d_in[14];
  const float* attn_out_w = (const float*)d_in[15];
  const float* attn_out_b = (const float*)d_in[16];
  const float* ff1_w = (const float*)d_in[17];
  const float* ff1_b = (const float*)d_in[18];
  const float* ff2_w = (const float*)d_in[19];
  const float* ff2_b = (const float*)d_in[20];
  const float* ln1_g = (const float*)d_in[21];
  const float* ln1_b = (const float*)d_in[22];
  const float* ln2_g = (const float*)d_in[23];
  const float* ln2_b = (const float*)d_in[24];
  const float* mlp1_w = (const float*)d_in[25];
  const float* mlp1_b = (const float*)d_in[26];
  const float* mlp2_w = (const float*)d_in[27];
  const float* mlp2_b = (const float*)d_in[28];

  // ---- small persistent buffers (floats) ----
  float* ws = (float*)d_ws;
  float* A1    = ws;                 // 663,552
  float* A2    = ws + 663552;        // 663,552
  float* SS    = ws + 1327104;       // 18,432
  float* SD    = ws + 1345536;       // 18,432
  float* SQB   = ws + 1363968;       // 512
  float* DSUM  = ws + 1364480;       // 64
  float* EMB   = ws + 1364544;       // 18,432
  float* FEAT  = ws + 1382976;       // 100,352
  float* FFEAT = ws + 1483328;       // 100,352
  // bf16 weight area (shorts), 16B-aligned
  short* wb = (short*)(ws + 1583680);
  short* W1T   = wb;                 // 746,496
  short* W2T   = wb + 746496;        // 746,496
  short* WTqkv = wb + 1492992;       // 153,600
  short* WTao  = wb + 1646592;       // 51,200
  short* WTf1  = wb + 1697792;       // 40,960
  short* WTf2  = wb + 1738752;       // 40,960
  const size_t CHBASE = 1583680 + 889856;   // = 2,473,536 floats
  float* CH = ws + CHBASE;

  // ---- pick largest chunk size that fits ws_size ----
  int CB = 8;
  const int cands[7] = {512, 256, 128, 64, 32, 16, 8};
  for (int c = 0; c < 7; ++c) {
    size_t need = 4ull * (CHBASE + 233920ull * (size_t)cands[c]);
    if (need <= ws_size) { CB = cands[c]; break; }
  }
  const int NCH = NB / CB;
  const int NTOKC = S_LEN * CB;

  float* XCH = CH;                         // 34,400*CB
  float* R0  = CH + (size_t)34400*CB;
  float* Xc  = R0;                         // 31,104*CB
  float* XPc = R0 + (size_t)31104*CB;      // 31,104*CB
  float* H1c = R0 + (size_t)62208*CB;      // 31,104*CB
  float* QKVc = R0;                        // 103,200*CB
  float* OAc  = R0 + (size_t)103200*CB;    // 34,400*CB
  float* Tc   = R0 + (size_t)137600*CB;    // 34,400*CB
  float* Yc   = R0 + (size_t)172000*CB;    // 27,520*CB

  hipMemsetAsync(DSUM, 0, 4, stream);
  zz_emb<<<dim3(CDIV(NB*DI,256)), 256, 0, stream>>>(statc, emb_w, emb_b, EMB);

  // ---- one-time weight transpose+bf16 conversions ----
  zz_wcvt<<<dim3(CDIV(FINP*FINP,256)), 256, 0, stream>>>(W1, W1T, FIN, FIN, FINP, FINP);
  zz_wcvt<<<dim3(CDIV(FINP*FINP,256)), 256, 0, stream>>>(W2, W2T, FIN, FIN, FINP, FINP);
  for (int l = 0; l < 2; ++l) {
    zz_wcvt<<<dim3(CDIV(480*160,256)), 256, 0, stream>>>(attn_in_w + (size_t)l*DT*3*DT,
        WTqkv + (size_t)l*76800, DT, 3*DT, DT, 3*DT);
    zz_wcvt<<<dim3(CDIV(160*160,256)), 256, 0, stream>>>(attn_out_w + (size_t)l*DT*DT,
        WTao + (size_t)l*25600, DT, DT, DT, DT);
    zz_wcvt<<<dim3(CDIV(128*160,256)), 256, 0, stream>>>(ff1_w + (size_t)l*DT*NHID,
        WTf1 + (size_t)l*20480, DT, NHID, DT, NHID);
    zz_wcvt<<<dim3(CDIV(160*128,256)), 256, 0, stream>>>(ff2_w + (size_t)l*NHID*DT,
        WTf2 + (size_t)l*20480, NHID, DT, NHID, DT);
  }

  for (int ch = 0; ch < NCH; ++ch) {
    int b0 = ch * CB;
    // ---- GAT stack (chunk) ----
    zz_build_x<<<dim3(CDIV(CB*DI*S_LEN,256)), 256, 0, stream>>>(src, R_u, Xc, b0, CB);
    zz_zeropad<<<dim3(CDIV(CB*DI,256)), 256, 0, stream>>>(Xc, CB);
    zz_gat_mfma<<<dim3(2, CB), 256, 0, stream>>>(Xc, W1T, XPc, CB);
    zz_gat_attvec<<<dim3(DI, CB), 64, 0, stream>>>(XPc, a1_s, a1_d, SS, SD, b0);
    zz_gat_alpha<<<dim3(CB), 256, 0, stream>>>(SS, SD, (const float*)nullptr, A1, b0);
    zz_gat_apply<<<dim3(4, CB), 256, 0, stream>>>(A1, XPc, H1c, 0, b0, CB);
    zz_zeropad<<<dim3(CDIV(CB*DI,256)), 256, 0, stream>>>(H1c, CB);
    zz_gat_mfma<<<dim3(2, CB), 256, 0, stream>>>(H1c, W2T, XPc, CB);
    zz_gat_attvec<<<dim3(DI, CB), 64, 0, stream>>>(XPc, a2_s, a2_d, SS, SD, b0);
    zz_gat_alpha<<<dim3(CB), 256, 0, stream>>>(SS, SD, A1, A2, b0);
    zz_gat_apply<<<dim3(4, CB), 256, 0, stream>>>(A2, XPc, XCH, 1, b0, CB);
    zz_pe<<<dim3(CDIV(CB*S_LEN*16,256)), 256, 0, stream>>>(times, XCH, b0, CB);

    // ---- transformer (chunk) ----
    for (int l = 0; l < 2; ++l) {
      zz_mgemm<0,0><<<dim3(CDIV(NTOKC,64)), 256, 0, stream>>>(XCH,
          WTqkv + (size_t)l*76800, attn_in_b + l*3*DT, nullptr, QKVc, NTOKC, 3*DT, DT);
      zz_attn<<<dim3(CB*NH), 256, 0, stream>>>(QKVc, lengths, OAc, b0, CB);
      zz_mgemm<0,1><<<dim3(CDIV(NTOKC,64)), 256, 0, stream>>>(OAc,
          WTao + (size_t)l*25600, attn_out_b + l*DT, XCH, Tc, NTOKC, DT, DT);
      zz_ln<<<dim3(CDIV(NTOKC,4)), 256, 0, stream>>>(Tc, ln1_g + l*DT, ln1_b + l*DT, XCH, NTOKC);
      zz_mgemm<1,0><<<dim3(CDIV(NTOKC,64)), 256, 0, stream>>>(XCH,
          WTf1 + (size_t)l*20480, ff1_b + l*NHID, nullptr, Yc, NTOKC, NHID, DT);
      zz_mgemm<0,1><<<dim3(CDIV(NTOKC,64)), 256, 0, stream>>>(Yc,
          WTf2 + (size_t)l*20480, ff2_b + l*DT, XCH, Tc, NTOKC, DT, NHID);
      zz_ln<<<dim3(CDIV(NTOKC,4)), 256, 0, stream>>>(Tc, ln2_g + l*DT, ln2_b + l*DT, XCH, NTOKC);
    }

    zz_agg<<<dim3(CB), 256, 0, stream>>>(XCH, lengths, EMB, FEAT, b0, CB);
  }

  // ---- distance from alpha2 (full batch) ----
  zz_sq<<<dim3(NB), 64, 0, stream>>>(A2, SQB);
  zz_dist<<<dim3(8, 8), 256, 0, stream>>>(A2, SQB, DSUM);
  zz_dist_fin<<<1, 1, 0, stream>>>(DSUM, (float*)d_out + 1024);

  // ---- head (f32, tiny) ----
  zz_gemm<1,0><<<dim3(CDIV(DFIN,128), CDIV(NB,64)), 256, 0, stream>>>(FEAT, mlp1_w, mlp1_b,
      nullptr, FFEAT, NB, DFIN, DFIN);
  zz_gemm<0,0><<<dim3(1, CDIV(NB,64)), 256, 0, stream>>>(FFEAT, mlp2_w, mlp2_b,
      nullptr, (float*)d_out, NB, 2, DFIN);
}